// Round 9
// baseline (444.563 us; speedup 1.0000x reference)
//
#include <hip/hip_runtime.h>
#include <hip/hip_bf16.h>
#include <math.h>

#define DIM   384
#define HEADS 12
#define HD    32
#define WIN   7
#define NPIX  49
#define IMG   56
#define NPF   3136   // IMG*IMG
#define NWIN  1024

typedef __attribute__((ext_vector_type(8))) short short8;
typedef __attribute__((ext_vector_type(4))) float f32x4;
#define MFMA __builtin_amdgcn_mfma_f32_16x16x32_bf16

__device__ inline ushort tob(float f) {
  unsigned u; __builtin_memcpy(&u, &f, 4);
  u += 0x7fffu + ((u >> 16) & 1u);
  return (ushort)(u >> 16);
}

// ---------------- bias table: bias[head][n][m] ----------------
__global__ void k_bias(const float* __restrict__ cpb, float* __restrict__ bias) {
  int idx = blockIdx.x * 256 + threadIdx.x;
  if (idx >= HEADS * NPIX * NPIX) return;
  int m = idx % NPIX;
  int n = (idx / NPIX) % NPIX;
  int h = idx / (NPIX * NPIX);
  int sy = (n / WIN - m / WIN) + (WIN - 1);
  int sx = (n % WIN - m % WIN) + (WIN - 1);
  const double inv_log_beta = 1.0 / log(1.3);
  double fy = (sy == 0 ? 0.0 : log1p((double)sy) * inv_log_beta) + 6.0;
  double fx = (sx == 0 ? 0.0 : log1p((double)sx) * inv_log_beta) + 6.0;
  fy = fmin(12.0, fmax(0.0, fy));
  fx = fmin(12.0, fmax(0.0, fx));
  int ridx = (int)(fy * 13.0 + fx);
  bias[idx] = cpb[ridx * HEADS + h];
}

// window-ordered source map: p' = (gy*8+gx)*49 + wy*7+wx -> rolled(+4) src pixel
__global__ void k_rmap(int* __restrict__ rmap) {
  int p = blockIdx.x * 256 + threadIdx.x;
  if (p < NPF) {
    int wb = p / NPIX, n = p - (p / NPIX) * NPIX;
    int gy = wb >> 3, gx = wb & 7;
    int wy = n / WIN, wx = n - (n / WIN) * WIN;
    rmap[p] = ((gy * WIN + wy + 4) % IMG) * IMG + (gx * WIN + wx + 4) % IMG;
  }
}

// ---------------- QKV projection: MFMA GEMM  qkv[b][o][p'] = W[o][:].Xr[:][p']
__global__ __launch_bounds__(256) void k_qkv(const float* __restrict__ x,
                                             const float* __restrict__ wqkv,
                                             const int* __restrict__ rmap,
                                             ushort* __restrict__ qkv) {
  __shared__ __align__(16) ushort sA[2][128 * 40];
  __shared__ __align__(16) ushort sB[2][128 * 40];
  __shared__ int srm[128];
  int t  = threadIdx.x;
  int o0 = blockIdx.x * 128;
  int p0 = blockIdx.y * 128;
  int b  = blockIdx.z;
  if (t < 128) { int pg = p0 + t; srm[t] = (pg < NPF) ? rmap[pg] : 0; }
  __syncthreads();

  int lane = t & 63, w = t >> 6;
  int wm = w >> 1, wn = w & 1;
  int l15 = lane & 15, l4 = lane >> 4;

  int ak = t & 31, ao = (t >> 5) << 4;
  int bp = t & 127, bc = (t >> 7) << 4;

  const float* xb = x + (size_t)b * DIM * NPF;

  f32x4 acc[4][4] = {};
  float av[16], bv[16];

  for (int i = 0; i < 16; ++i) av[i] = wqkv[(size_t)(o0 + ao + i) * DIM + ak];
  for (int i = 0; i < 16; ++i) bv[i] = xb[(size_t)(bc + i) * NPF + srm[bp]];
  for (int i = 0; i < 16; ++i) sA[0][(ao + i) * 40 + ak] = tob(av[i]);
  for (int i = 0; i < 16; ++i) sB[0][bp * 40 + bc + i] = tob(bv[i]);

  for (int ks = 0; ks < 12; ++ks) {
    __syncthreads();
    int cur = ks & 1;
    if (ks < 11) {
      int k0 = (ks + 1) * 32;
      for (int i = 0; i < 16; ++i) av[i] = wqkv[(size_t)(o0 + ao + i) * DIM + k0 + ak];
      for (int i = 0; i < 16; ++i) bv[i] = xb[(size_t)(k0 + bc + i) * NPF + srm[bp]];
    }
    short8 af[4], bfr[4];
    for (int mi = 0; mi < 4; ++mi)
      af[mi] = *(const short8*)&sA[cur][(wm * 64 + mi * 16 + l15) * 40 + l4 * 8];
    for (int ni = 0; ni < 4; ++ni)
      bfr[ni] = *(const short8*)&sB[cur][(wn * 64 + ni * 16 + l15) * 40 + l4 * 8];
    for (int mi = 0; mi < 4; ++mi)
      for (int ni = 0; ni < 4; ++ni)
        acc[mi][ni] = MFMA(af[mi], bfr[ni], acc[mi][ni], 0, 0, 0);
    if (ks < 11) {
      int nxt = cur ^ 1;
      for (int i = 0; i < 16; ++i) sA[nxt][(ao + i) * 40 + ak] = tob(av[i]);
      for (int i = 0; i < 16; ++i) sB[nxt][bp * 40 + bc + i] = bv[i] == bv[i] ? tob(bv[i]) : (ushort)0;
    }
  }

  for (int mi = 0; mi < 4; ++mi)
    for (int ni = 0; ni < 4; ++ni)
      for (int r = 0; r < 4; ++r) {
        int o = o0 + wm * 64 + mi * 16 + (l4 << 2) + r;
        int p = p0 + wn * 64 + ni * 16 + l15;
        if (p < NPF)
          qkv[((size_t)b * 1152 + o) * NPF + p] = tob(acc[mi][ni][r]);
      }
}

// ---------------- MFMA attention per (window, head), 1 wave ----------------
// Window-ordered layout: contiguous loads; in-register softmax.
__global__ __launch_bounds__(64) void k_attn(ushort* __restrict__ qkv,
                                             const float* __restrict__ bias) {
  __shared__ __align__(16) ushort smem[8992];   // 17984 B
  ushort* sq  = smem;          // [64][40]
  ushort* skt = smem + 2560;   // [64][40]
  ushort* svt = smem + 5120;   // [32][72]  V^T rows d, cols m
  ushort* stg = smem + 7424;   // [32*49] d-major staging
  ushort* pa  = smem;          // [64][72]  P bf16 (overlays sq/skt)

  int t = threadIdx.x;
  int bid = blockIdx.x;
  int h = bid % HEADS, wb = bid / HEADS;
  int b = wb >> 6;
  int w49 = (wb & 63) * NPIX;
  size_t qb = ((size_t)b * 1152 + h * HD) * NPF;
  size_t kb = qb + (size_t)DIM * NPF;
  size_t vb = qb + (size_t)(2 * DIM) * NPF;

  // phase 0: zero svt tail; stage Q (d-major contiguous)
  for (int idx = t; idx < 32 * 23; idx += 64) {
    int d = idx / 23, mm = 49 + (idx - d * 23);
    svt[d * 72 + mm] = 0;
  }
  for (int idx = t; idx < HD * NPIX; idx += 64) stg[idx] = qkv[qb + (size_t)(idx / NPIX) * NPF + w49 + (idx % NPIX)];
  __syncthreads();
  // phase 1: transpose Q -> sq; stage V -> svt
  for (int idx = t; idx < HD * NPIX; idx += 64) {
    int d = idx / NPIX, n = idx - d * NPIX;
    sq[n * 40 + d] = stg[idx];
  }
  for (int idx = t; idx < HD * NPIX; idx += 64) {
    int d = idx / NPIX, m = idx - d * NPIX;
    svt[d * 72 + m] = qkv[vb + (size_t)d * NPF + w49 + m];
  }
  __syncthreads();
  // phase 2: stage K
  for (int idx = t; idx < HD * NPIX; idx += 64) stg[idx] = qkv[kb + (size_t)(idx / NPIX) * NPF + w49 + (idx % NPIX)];
  __syncthreads();
  // phase 3: transpose K -> skt
  for (int idx = t; idx < HD * NPIX; idx += 64) {
    int d = idx / NPIX, m = idx - d * NPIX;
    skt[m * 40 + d] = stg[idx];
  }
  __syncthreads();

  int l15 = t & 15, l4 = t >> 4;
  f32x4 acc[4][4] = {};
  {
    short8 af[4], bfr[4];
#pragma unroll
    for (int mi = 0; mi < 4; ++mi) af[mi]  = *(const short8*)&sq [(mi * 16 + l15) * 40 + l4 * 8];
#pragma unroll
    for (int ni = 0; ni < 4; ++ni) bfr[ni] = *(const short8*)&skt[(ni * 16 + l15) * 40 + l4 * 8];
#pragma unroll
    for (int mi = 0; mi < 4; ++mi)
#pragma unroll
      for (int ni = 0; ni < 4; ++ni)
        acc[mi][ni] = MFMA(af[mi], bfr[ni], acc[mi][ni], 0, 0, 0);
  }

  // in-register softmax. lane holds rows n = mi*16 + l4*4 + r, cols m = ni*16 + l15.
  const float scale = 0.17677669529663687f;
  const float* bh = bias + h * NPIX * NPIX;
  float mx[16], sm[16];
#pragma unroll
  for (int mi = 0; mi < 4; ++mi)
#pragma unroll
    for (int r = 0; r < 4; ++r) {
      int n = mi * 16 + (l4 << 2) + r;
      float vmax = -3e38f;
#pragma unroll
      for (int ni = 0; ni < 4; ++ni) {
        int m = ni * 16 + l15;
        float s = (m < NPIX)
                    ? acc[mi][ni][r] * scale + ((n < NPIX) ? bh[n * NPIX + m] : 0.f)
                    : -3e38f;
        acc[mi][ni][r] = s;
        vmax = fmaxf(vmax, s);
      }
      mx[mi * 4 + r] = vmax;
    }
#pragma unroll
  for (int i = 1; i < 16; i <<= 1)
#pragma unroll
    for (int j = 0; j < 16; ++j) mx[j] = fmaxf(mx[j], __shfl_xor(mx[j], i));
#pragma unroll
  for (int mi = 0; mi < 4; ++mi)
#pragma unroll
    for (int r = 0; r < 4; ++r) {
      float s = 0.f;
#pragma unroll
      for (int ni = 0; ni < 4; ++ni) {
        float e = expf(acc[mi][ni][r] - mx[mi * 4 + r]);
        acc[mi][ni][r] = e;
        s += e;
      }
      sm[mi * 4 + r] = s;
    }
#pragma unroll
  for (int i = 1; i < 16; i <<= 1)
#pragma unroll
    for (int j = 0; j < 16; ++j) sm[j] += __shfl_xor(sm[j], i);

  __syncthreads();   // sq/skt frag reads done; safe to overwrite with pa
#pragma unroll
  for (int mi = 0; mi < 4; ++mi)
#pragma unroll
    for (int r = 0; r < 4; ++r) {
      float ri = 1.f / sm[mi * 4 + r];
      int n = mi * 16 + (l4 << 2) + r;
#pragma unroll
      for (int ni = 0; ni < 4; ++ni)
        pa[n * 72 + ni * 16 + l15] = tob(acc[mi][ni][r] * ri);
    }
  __syncthreads();

  f32x4 yac[4][2] = {};
#pragma unroll
  for (int ks = 0; ks < 2; ++ks) {
    short8 pf[4], vf[2];
#pragma unroll
    for (int mi = 0; mi < 4; ++mi) pf[mi] = *(const short8*)&pa [(mi * 16 + l15) * 72 + ks * 32 + l4 * 8];
#pragma unroll
    for (int nd = 0; nd < 2; ++nd) vf[nd] = *(const short8*)&svt[(nd * 16 + l15) * 72 + ks * 32 + l4 * 8];
#pragma unroll
    for (int mi = 0; mi < 4; ++mi)
#pragma unroll
      for (int nd = 0; nd < 2; ++nd)
        yac[mi][nd] = MFMA(pf[mi], vf[nd], yac[mi][nd], 0, 0, 0);
  }
  // Y over Q slice, contiguous in n
#pragma unroll
  for (int mi = 0; mi < 4; ++mi)
#pragma unroll
    for (int nd = 0; nd < 2; ++nd) {
      int nb = mi * 16 + (l4 << 2);
      int d = nd * 16 + l15;
      size_t ga = qb + (size_t)d * NPF + w49 + nb;
#pragma unroll
      for (int r = 0; r < 4; ++r)
        if (nb + r < NPIX) qkv[ga + r] = tob(yac[mi][nd][r]);
    }
}

// ---------------- output projection: MFMA GEMM out[b][o][p] = Wp . Y ----------
__global__ __launch_bounds__(256) void k_proj(const ushort* __restrict__ yq,
                                              const float* __restrict__ wproj,
                                              float* __restrict__ out) {
  __shared__ __align__(16) ushort sA[2][128 * 40];
  __shared__ __align__(16) ushort sB[2][128 * 40];
  __shared__ int srm[128];
  int t  = threadIdx.x;
  int o0 = blockIdx.x * 128;
  int p0 = blockIdx.y * 128;
  int b  = blockIdx.z;
  if (t < 128) {
    int pg = p0 + t;
    if (pg >= NPF) pg = 0;
    int si = (pg / IMG + 53) % IMG, sj = (pg % IMG + 53) % IMG;  // inverse roll +3
    srm[t] = ((si / WIN) * 8 + sj / WIN) * NPIX + (si % WIN) * WIN + (sj % WIN);
  }
  __syncthreads();

  int lane = t & 63, w = t >> 6;
  int wm = w >> 1, wn = w & 1;
  int l15 = lane & 15, l4 = lane >> 4;

  int ak = t & 31, ao = (t >> 5) << 4;
  int bp = t & 127, bc = (t >> 7) << 4;

  const ushort* yb = yq + (size_t)b * 1152 * NPF;

  f32x4 acc[4][4] = {};
  float av[16];
  ushort bv[16];

  for (int i = 0; i < 16; ++i) av[i] = wproj[(size_t)(o0 + ao + i) * DIM + ak];
  for (int i = 0; i < 16; ++i) bv[i] = yb[(size_t)(bc + i) * NPF + srm[bp]];
  for (int i = 0; i < 16; ++i) sA[0][(ao + i) * 40 + ak] = tob(av[i]);
  for (int i = 0; i < 16; ++i) sB[0][bp * 40 + bc + i] = bv[i];

  for (int ks = 0; ks < 12; ++ks) {
    __syncthreads();
    int cur = ks & 1;
    if (ks < 11) {
      int k0 = (ks + 1) * 32;
      for (int i = 0; i < 16; ++i) av[i] = wproj[(size_t)(o0 + ao + i) * DIM + k0 + ak];
      for (int i = 0; i < 16; ++i) bv[i] = yb[(size_t)(k0 + bc + i) * NPF + srm[bp]];
    }
    short8 af[4], bfr[4];
    for (int mi = 0; mi < 4; ++mi)
      af[mi] = *(const short8*)&sA[cur][(wm * 64 + mi * 16 + l15) * 40 + l4 * 8];
    for (int ni = 0; ni < 4; ++ni)
      bfr[ni] = *(const short8*)&sB[cur][(wn * 64 + ni * 16 + l15) * 40 + l4 * 8];
    for (int mi = 0; mi < 4; ++mi)
      for (int ni = 0; ni < 4; ++ni)
        acc[mi][ni] = MFMA(af[mi], bfr[ni], acc[mi][ni], 0, 0, 0);
    if (ks < 11) {
      int nxt = cur ^ 1;
      for (int i = 0; i < 16; ++i) sA[nxt][(ao + i) * 40 + ak] = tob(av[i]);
      for (int i = 0; i < 16; ++i) sB[nxt][bp * 40 + bc + i] = bv[i];
    }
  }

  for (int mi = 0; mi < 4; ++mi)
    for (int ni = 0; ni < 4; ++ni)
      for (int r = 0; r < 4; ++r) {
        int o = o0 + wm * 64 + mi * 16 + (l4 << 2) + r;
        int p = p0 + wn * 64 + ni * 16 + l15;
        if (p < NPF)
          out[((size_t)b * DIM + o) * NPF + p] = acc[mi][ni][r];
      }
}

extern "C" void kernel_launch(void* const* d_in, const int* in_sizes, int n_in,
                              void* d_out, int out_size, void* d_ws, size_t ws_size,
                              hipStream_t stream) {
  const float* x     = (const float*)d_in[0];
  const float* wqkv  = (const float*)d_in[1];
  const float* wproj = (const float*)d_in[2];
  const float* cpb   = (const float*)d_in[3];
  float* out = (float*)d_out;

  char* ws = (char*)d_ws;
  float* bias  = (float*)ws;                 // 115248 B
  int*   rmap  = (int*)(ws + 115712);
  ushort* qkv  = (ushort*)(ws + 131072);     // 115.6 MB

  hipLaunchKernelGGL(k_bias, dim3(113), dim3(256), 0, stream, cpb, bias);
  hipLaunchKernelGGL(k_rmap, dim3(13), dim3(256), 0, stream, rmap);
  hipLaunchKernelGGL(k_qkv, dim3(9, 25, 16), dim3(256), 0, stream, x, wqkv, rmap, qkv);
  hipLaunchKernelGGL(k_attn, dim3(NWIN * HEADS), dim3(64), 0, stream, qkv, bias);
  hipLaunchKernelGGL(k_proj, dim3(3, 25, 16), dim3(256), 0, stream, qkv, wproj, out);
}

// Round 10
// 404.202 us; speedup vs baseline: 1.0999x; 1.0999x over previous
//
#include <hip/hip_runtime.h>
#include <hip/hip_bf16.h>
#include <math.h>

#define DIM   384
#define HEADS 12
#define HD    32
#define WIN   7
#define NPIX  49
#define IMG   56
#define NPF   3136   // IMG*IMG
#define NWIN  1024

typedef __attribute__((ext_vector_type(8))) short short8;
typedef __attribute__((ext_vector_type(4))) float f32x4;
typedef __attribute__((ext_vector_type(4))) float f4;
typedef __attribute__((ext_vector_type(4))) unsigned short us4;
typedef __attribute__((ext_vector_type(8))) unsigned short us8;
#define MFMA __builtin_amdgcn_mfma_f32_16x16x32_bf16

__device__ inline ushort tob(float f) {
  unsigned u; __builtin_memcpy(&u, &f, 4);
  u += 0x7fffu + ((u >> 16) & 1u);
  return (ushort)(u >> 16);
}

// ---------------- bias table: bias[head][n][m] ----------------
__global__ void k_bias(const float* __restrict__ cpb, float* __restrict__ bias) {
  int idx = blockIdx.x * 256 + threadIdx.x;
  if (idx >= HEADS * NPIX * NPIX) return;
  int m = idx % NPIX;
  int n = (idx / NPIX) % NPIX;
  int h = idx / (NPIX * NPIX);
  int sy = (n / WIN - m / WIN) + (WIN - 1);
  int sx = (n % WIN - m % WIN) + (WIN - 1);
  const double inv_log_beta = 1.0 / log(1.3);
  double fy = (sy == 0 ? 0.0 : log1p((double)sy) * inv_log_beta) + 6.0;
  double fx = (sx == 0 ? 0.0 : log1p((double)sx) * inv_log_beta) + 6.0;
  fy = fmin(12.0, fmax(0.0, fy));
  fx = fmin(12.0, fmax(0.0, fx));
  int ridx = (int)(fy * 13.0 + fx);
  bias[idx] = cpb[ridx * HEADS + h];
}

// window-ordered source map: p' = (gy*8+gx)*49 + wy*7+wx -> rolled(+4) src pixel
__global__ void k_rmap(int* __restrict__ rmap) {
  int p = blockIdx.x * 256 + threadIdx.x;
  if (p < NPF) {
    int wb = p / NPIX, n = p - (p / NPIX) * NPIX;
    int gy = wb >> 3, gx = wb & 7;
    int wy = n / WIN, wx = n - (n / WIN) * WIN;
    rmap[p] = ((gy * WIN + wy + 4) % IMG) * IMG + (gx * WIN + wx + 4) % IMG;
  }
}

// ---------------- QKV projection: MFMA GEMM  qkv[b][o][p'] = W[o][:].Xr[:][p']
// 1D grid 3600, XCD-swizzled: each XCD owns contiguous (b,ptile) range, o fastest
__global__ __launch_bounds__(256) void k_qkv(const float* __restrict__ x,
                                             const float* __restrict__ wqkv,
                                             const int* __restrict__ rmap,
                                             ushort* __restrict__ qkv) {
  __shared__ __align__(16) ushort sA[2][128 * 40];
  __shared__ __align__(16) ushort sB[2][128 * 40];
  __shared__ int srm[128];
  int t   = threadIdx.x;
  int bid = blockIdx.x;
  int swz = (bid & 7) * 450 + (bid >> 3);   // 3600 = 8*450, bijective
  int o0  = (swz % 9) * 128;                // o fastest within XCD chunk
  int pb  = swz / 9;
  int p0  = (pb % 25) * 128;
  int b   = pb / 25;
  if (t < 128) { int pg = p0 + t; srm[t] = rmap[(pg < NPF) ? pg : (NPF - 1)]; }
  __syncthreads();

  int lane = t & 63, w = t >> 6;
  int wm = w >> 1, wn = w & 1;
  int l15 = lane & 15, l4 = lane >> 4;

  int k4 = (t & 7) * 4, ar = t >> 3;       // A stage: 4 float4 rows ar+32i
  int bp = t & 127, bc = (t >> 7) << 4;    // B stage: pixel bp, 16 chans

  const float* xb = x + (size_t)b * DIM * NPF;

  f32x4 acc[4][4] = {};

  // prologue: stage k-step 0
  {
#pragma unroll
    for (int i = 0; i < 4; ++i) {
      int row = ar + 32 * i;
      f4 v = *(const f4*)&wqkv[(size_t)(o0 + row) * DIM + k4];
      us4 u; u[0] = tob(v[0]); u[1] = tob(v[1]); u[2] = tob(v[2]); u[3] = tob(v[3]);
      *(us4*)&sA[0][row * 40 + k4] = u;
    }
    int sp = srm[bp];
    us8 u0, u1;
#pragma unroll
    for (int i = 0; i < 8; ++i) u0[i] = tob(xb[(size_t)(bc + i) * NPF + sp]);
#pragma unroll
    for (int i = 0; i < 8; ++i) u1[i] = tob(xb[(size_t)(bc + 8 + i) * NPF + sp]);
    *(us8*)&sB[0][bp * 40 + bc] = u0;
    *(us8*)&sB[0][bp * 40 + bc + 8] = u1;
  }

  for (int ks = 0; ks < 12; ++ks) {
    __syncthreads();
    int cur = ks & 1;
    f4 aw[4]; float bw[16];
    if (ks < 11) {
      int k0 = (ks + 1) * 32;
#pragma unroll
      for (int i = 0; i < 4; ++i)
        aw[i] = *(const f4*)&wqkv[(size_t)(o0 + ar + 32 * i) * DIM + k0 + k4];
      int sp = srm[bp];
#pragma unroll
      for (int i = 0; i < 16; ++i)
        bw[i] = xb[(size_t)(k0 + bc + i) * NPF + sp];
    }
    short8 af[4], bfr[4];
#pragma unroll
    for (int mi = 0; mi < 4; ++mi)
      af[mi] = *(const short8*)&sA[cur][(wm * 64 + mi * 16 + l15) * 40 + l4 * 8];
#pragma unroll
    for (int ni = 0; ni < 4; ++ni)
      bfr[ni] = *(const short8*)&sB[cur][(wn * 64 + ni * 16 + l15) * 40 + l4 * 8];
#pragma unroll
    for (int mi = 0; mi < 4; ++mi)
#pragma unroll
      for (int ni = 0; ni < 4; ++ni)
        acc[mi][ni] = MFMA(af[mi], bfr[ni], acc[mi][ni], 0, 0, 0);
    if (ks < 11) {
      int nxt = cur ^ 1;
#pragma unroll
      for (int i = 0; i < 4; ++i) {
        us4 u; u[0] = tob(aw[i][0]); u[1] = tob(aw[i][1]); u[2] = tob(aw[i][2]); u[3] = tob(aw[i][3]);
        *(us4*)&sA[nxt][(ar + 32 * i) * 40 + k4] = u;
      }
      us8 u0, u1;
#pragma unroll
      for (int i = 0; i < 8; ++i) u0[i] = tob(bw[i]);
#pragma unroll
      for (int i = 0; i < 8; ++i) u1[i] = tob(bw[8 + i]);
      *(us8*)&sB[nxt][bp * 40 + bc] = u0;
      *(us8*)&sB[nxt][bp * 40 + bc + 8] = u1;
    }
  }

  for (int mi = 0; mi < 4; ++mi)
    for (int ni = 0; ni < 4; ++ni)
      for (int r = 0; r < 4; ++r) {
        int o = o0 + wm * 64 + mi * 16 + (l4 << 2) + r;
        int p = p0 + wn * 64 + ni * 16 + l15;
        if (p < NPF)
          qkv[((size_t)b * 1152 + o) * NPF + p] = tob(acc[mi][ni][r]);
      }
}

// ---------------- MFMA attention per (window, head), 1 wave ----------------
__global__ __launch_bounds__(64) void k_attn(ushort* __restrict__ qkv,
                                             const float* __restrict__ bias) {
  __shared__ __align__(16) ushort smem[8992];   // 17984 B
  ushort* sq  = smem;          // [64][40]
  ushort* skt = smem + 2560;   // [64][40]
  ushort* svt = smem + 5120;   // [32][72]  V^T rows d, cols m
  ushort* stg = smem + 7424;   // [32*49] d-major staging
  ushort* pa  = smem;          // [64][72]  P bf16 (overlays sq/skt)

  int t = threadIdx.x;
  int bid = blockIdx.x;
  int h = bid % HEADS, wb = bid / HEADS;
  int b = wb >> 6;
  int w49 = (wb & 63) * NPIX;
  size_t qb = ((size_t)b * 1152 + h * HD) * NPF;
  size_t kb = qb + (size_t)DIM * NPF;
  size_t vb = qb + (size_t)(2 * DIM) * NPF;

  for (int idx = t; idx < 32 * 23; idx += 64) {
    int d = idx / 23, mm = 49 + (idx - d * 23);
    svt[d * 72 + mm] = 0;
  }
  for (int idx = t; idx < HD * NPIX; idx += 64) stg[idx] = qkv[qb + (size_t)(idx / NPIX) * NPF + w49 + (idx % NPIX)];
  __syncthreads();
  for (int idx = t; idx < HD * NPIX; idx += 64) {
    int d = idx / NPIX, n = idx - d * NPIX;
    sq[n * 40 + d] = stg[idx];
  }
  for (int idx = t; idx < HD * NPIX; idx += 64) {
    int d = idx / NPIX, m = idx - d * NPIX;
    svt[d * 72 + m] = qkv[vb + (size_t)d * NPF + w49 + m];
  }
  __syncthreads();
  for (int idx = t; idx < HD * NPIX; idx += 64) stg[idx] = qkv[kb + (size_t)(idx / NPIX) * NPF + w49 + (idx % NPIX)];
  __syncthreads();
  for (int idx = t; idx < HD * NPIX; idx += 64) {
    int d = idx / NPIX, m = idx - d * NPIX;
    skt[m * 40 + d] = stg[idx];
  }
  __syncthreads();

  int l15 = t & 15, l4 = t >> 4;
  f32x4 acc[4][4] = {};
  {
    short8 af[4], bfr[4];
#pragma unroll
    for (int mi = 0; mi < 4; ++mi) af[mi]  = *(const short8*)&sq [(mi * 16 + l15) * 40 + l4 * 8];
#pragma unroll
    for (int ni = 0; ni < 4; ++ni) bfr[ni] = *(const short8*)&skt[(ni * 16 + l15) * 40 + l4 * 8];
#pragma unroll
    for (int mi = 0; mi < 4; ++mi)
#pragma unroll
      for (int ni = 0; ni < 4; ++ni)
        acc[mi][ni] = MFMA(af[mi], bfr[ni], acc[mi][ni], 0, 0, 0);
  }

  const float scale = 0.17677669529663687f;
  const float* bh = bias + h * NPIX * NPIX;
  float mx[16], sm[16];
#pragma unroll
  for (int mi = 0; mi < 4; ++mi)
#pragma unroll
    for (int r = 0; r < 4; ++r) {
      int n = mi * 16 + (l4 << 2) + r;
      float vmax = -3e38f;
#pragma unroll
      for (int ni = 0; ni < 4; ++ni) {
        int m = ni * 16 + l15;
        float s = (m < NPIX)
                    ? acc[mi][ni][r] * scale + ((n < NPIX) ? bh[n * NPIX + m] : 0.f)
                    : -3e38f;
        acc[mi][ni][r] = s;
        vmax = fmaxf(vmax, s);
      }
      mx[mi * 4 + r] = vmax;
    }
#pragma unroll
  for (int i = 1; i < 16; i <<= 1)
#pragma unroll
    for (int j = 0; j < 16; ++j) mx[j] = fmaxf(mx[j], __shfl_xor(mx[j], i));
#pragma unroll
  for (int mi = 0; mi < 4; ++mi)
#pragma unroll
    for (int r = 0; r < 4; ++r) {
      float s = 0.f;
#pragma unroll
      for (int ni = 0; ni < 4; ++ni) {
        float e = expf(acc[mi][ni][r] - mx[mi * 4 + r]);
        acc[mi][ni][r] = e;
        s += e;
      }
      sm[mi * 4 + r] = s;
    }
#pragma unroll
  for (int i = 1; i < 16; i <<= 1)
#pragma unroll
    for (int j = 0; j < 16; ++j) sm[j] += __shfl_xor(sm[j], i);

  __syncthreads();
#pragma unroll
  for (int mi = 0; mi < 4; ++mi)
#pragma unroll
    for (int r = 0; r < 4; ++r) {
      float ri = 1.f / sm[mi * 4 + r];
      int n = mi * 16 + (l4 << 2) + r;
#pragma unroll
      for (int ni = 0; ni < 4; ++ni)
        pa[n * 72 + ni * 16 + l15] = tob(acc[mi][ni][r] * ri);
    }
  __syncthreads();

  f32x4 yac[4][2] = {};
#pragma unroll
  for (int ks = 0; ks < 2; ++ks) {
    short8 pf[4], vf[2];
#pragma unroll
    for (int mi = 0; mi < 4; ++mi) pf[mi] = *(const short8*)&pa [(mi * 16 + l15) * 72 + ks * 32 + l4 * 8];
#pragma unroll
    for (int nd = 0; nd < 2; ++nd) vf[nd] = *(const short8*)&svt[(nd * 16 + l15) * 72 + ks * 32 + l4 * 8];
#pragma unroll
    for (int mi = 0; mi < 4; ++mi)
#pragma unroll
      for (int nd = 0; nd < 2; ++nd)
        yac[mi][nd] = MFMA(pf[mi], vf[nd], yac[mi][nd], 0, 0, 0);
  }
#pragma unroll
  for (int mi = 0; mi < 4; ++mi)
#pragma unroll
    for (int nd = 0; nd < 2; ++nd) {
      int nb = mi * 16 + (l4 << 2);
      int d = nd * 16 + l15;
      size_t ga = qb + (size_t)d * NPF + w49 + nb;
#pragma unroll
      for (int r = 0; r < 4; ++r)
        if (nb + r < NPIX) qkv[ga + r] = tob(yac[mi][nd][r]);
    }
}

// ---------------- output projection: MFMA GEMM out[b][o][p] = Wp . Y ----------
// 1D grid 1200, XCD-swizzled: o fastest within XCD chunk
__global__ __launch_bounds__(256) void k_proj(const ushort* __restrict__ yq,
                                              const float* __restrict__ wproj,
                                              float* __restrict__ out) {
  __shared__ __align__(16) ushort sA[2][128 * 40];
  __shared__ __align__(16) ushort sB[2][128 * 40];
  __shared__ int srm[128];
  int t   = threadIdx.x;
  int bid = blockIdx.x;
  int swz = (bid & 7) * 150 + (bid >> 3);   // 1200 = 8*150, bijective
  int o0  = (swz % 3) * 128;
  int pb  = swz / 3;
  int p0  = (pb % 25) * 128;
  int b   = pb / 25;
  if (t < 128) {
    int pg = p0 + t;
    if (pg >= NPF) pg = 0;
    int si = (pg / IMG + 53) % IMG, sj = (pg % IMG + 53) % IMG;  // inverse roll +3
    srm[t] = ((si / WIN) * 8 + sj / WIN) * NPIX + (si % WIN) * WIN + (sj % WIN);
  }
  __syncthreads();

  int lane = t & 63, w = t >> 6;
  int wm = w >> 1, wn = w & 1;
  int l15 = lane & 15, l4 = lane >> 4;

  int k4 = (t & 7) * 4, ar = t >> 3;
  int bp = t & 127, bc = (t >> 7) << 4;

  const ushort* yb = yq + (size_t)b * 1152 * NPF;

  f32x4 acc[4][4] = {};

  {
#pragma unroll
    for (int i = 0; i < 4; ++i) {
      int row = ar + 32 * i;
      f4 v = *(const f4*)&wproj[(size_t)(o0 + row) * DIM + k4];
      us4 u; u[0] = tob(v[0]); u[1] = tob(v[1]); u[2] = tob(v[2]); u[3] = tob(v[3]);
      *(us4*)&sA[0][row * 40 + k4] = u;
    }
    int sp = srm[bp];
    us8 u0, u1;
#pragma unroll
    for (int i = 0; i < 8; ++i) u0[i] = yb[(size_t)(bc + i) * NPF + sp];
#pragma unroll
    for (int i = 0; i < 8; ++i) u1[i] = yb[(size_t)(bc + 8 + i) * NPF + sp];
    *(us8*)&sB[0][bp * 40 + bc] = u0;
    *(us8*)&sB[0][bp * 40 + bc + 8] = u1;
  }

  for (int ks = 0; ks < 12; ++ks) {
    __syncthreads();
    int cur = ks & 1;
    f4 aw[4]; ushort bw[16];
    if (ks < 11) {
      int k0 = (ks + 1) * 32;
#pragma unroll
      for (int i = 0; i < 4; ++i)
        aw[i] = *(const f4*)&wproj[(size_t)(o0 + ar + 32 * i) * DIM + k0 + k4];
      int sp = srm[bp];
#pragma unroll
      for (int i = 0; i < 16; ++i)
        bw[i] = yb[(size_t)(k0 + bc + i) * NPF + sp];
    }
    short8 af[4], bfr[4];
#pragma unroll
    for (int mi = 0; mi < 4; ++mi)
      af[mi] = *(const short8*)&sA[cur][(wm * 64 + mi * 16 + l15) * 40 + l4 * 8];
#pragma unroll
    for (int ni = 0; ni < 4; ++ni)
      bfr[ni] = *(const short8*)&sB[cur][(wn * 64 + ni * 16 + l15) * 40 + l4 * 8];
#pragma unroll
    for (int mi = 0; mi < 4; ++mi)
#pragma unroll
      for (int ni = 0; ni < 4; ++ni)
        acc[mi][ni] = MFMA(af[mi], bfr[ni], acc[mi][ni], 0, 0, 0);
    if (ks < 11) {
      int nxt = cur ^ 1;
#pragma unroll
      for (int i = 0; i < 4; ++i) {
        us4 u; u[0] = tob(aw[i][0]); u[1] = tob(aw[i][1]); u[2] = tob(aw[i][2]); u[3] = tob(aw[i][3]);
        *(us4*)&sA[nxt][(ar + 32 * i) * 40 + k4] = u;
      }
      us8 u0, u1;
#pragma unroll
      for (int i = 0; i < 8; ++i) u0[i] = bw[i];
#pragma unroll
      for (int i = 0; i < 8; ++i) u1[i] = bw[8 + i];
      *(us8*)&sB[nxt][bp * 40 + bc] = u0;
      *(us8*)&sB[nxt][bp * 40 + bc + 8] = u1;
    }
  }

  for (int mi = 0; mi < 4; ++mi)
    for (int ni = 0; ni < 4; ++ni)
      for (int r = 0; r < 4; ++r) {
        int o = o0 + wm * 64 + mi * 16 + (l4 << 2) + r;
        int p = p0 + wn * 64 + ni * 16 + l15;
        if (p < NPF)
          out[((size_t)b * DIM + o) * NPF + p] = acc[mi][ni][r];
      }
}

extern "C" void kernel_launch(void* const* d_in, const int* in_sizes, int n_in,
                              void* d_out, int out_size, void* d_ws, size_t ws_size,
                              hipStream_t stream) {
  const float* x     = (const float*)d_in[0];
  const float* wqkv  = (const float*)d_in[1];
  const float* wproj = (const float*)d_in[2];
  const float* cpb   = (const float*)d_in[3];
  float* out = (float*)d_out;

  char* ws = (char*)d_ws;
  float* bias  = (float*)ws;                 // 115248 B
  int*   rmap  = (int*)(ws + 115712);
  ushort* qkv  = (ushort*)(ws + 131072);     // 115.6 MB

  hipLaunchKernelGGL(k_bias, dim3(113), dim3(256), 0, stream, cpb, bias);
  hipLaunchKernelGGL(k_rmap, dim3(13), dim3(256), 0, stream, rmap);
  hipLaunchKernelGGL(k_qkv, dim3(3600), dim3(256), 0, stream, x, wqkv, rmap, qkv);
  hipLaunchKernelGGL(k_attn, dim3(NWIN * HEADS), dim3(64), 0, stream, qkv, bias);
  hipLaunchKernelGGL(k_proj, dim3(1200), dim3(256), 0, stream, qkv, wproj, out);
}

// Round 11
// 321.576 us; speedup vs baseline: 1.3824x; 1.2569x over previous
//
#include <hip/hip_runtime.h>
#include <hip/hip_bf16.h>
#include <math.h>

#define DIM   384
#define HEADS 12
#define HD    32
#define WIN   7
#define NPIX  49
#define IMG   56
#define NPF   3136   // IMG*IMG
#define NWIN  1024

typedef __attribute__((ext_vector_type(8))) short short8;
typedef __attribute__((ext_vector_type(4))) float f32x4;
typedef __attribute__((ext_vector_type(4))) float f4;
typedef __attribute__((ext_vector_type(4))) unsigned short us4;
typedef __attribute__((ext_vector_type(8))) unsigned short us8;
#define MFMA __builtin_amdgcn_mfma_f32_16x16x32_bf16

__device__ inline ushort tob(float f) {
  unsigned u; __builtin_memcpy(&u, &f, 4);
  u += 0x7fffu + ((u >> 16) & 1u);
  return (ushort)(u >> 16);
}

// ---------------- bias table ----------------
__global__ void k_bias(const float* __restrict__ cpb, float* __restrict__ bias) {
  int idx = blockIdx.x * 256 + threadIdx.x;
  if (idx >= HEADS * NPIX * NPIX) return;
  int m = idx % NPIX;
  int n = (idx / NPIX) % NPIX;
  int h = idx / (NPIX * NPIX);
  int sy = (n / WIN - m / WIN) + (WIN - 1);
  int sx = (n % WIN - m % WIN) + (WIN - 1);
  const double inv_log_beta = 1.0 / log(1.3);
  double fy = (sy == 0 ? 0.0 : log1p((double)sy) * inv_log_beta) + 6.0;
  double fx = (sx == 0 ? 0.0 : log1p((double)sx) * inv_log_beta) + 6.0;
  fy = fmin(12.0, fmax(0.0, fy));
  fx = fmin(12.0, fmax(0.0, fx));
  int ridx = (int)(fy * 13.0 + fx);
  bias[idx] = cpb[ridx * HEADS + h];
}

__global__ void k_rmap(int* __restrict__ rmap) {
  int p = blockIdx.x * 256 + threadIdx.x;
  if (p < NPF) {
    int wb = p / NPIX, n = p - (p / NPIX) * NPIX;
    int gy = wb >> 3, gx = wb & 7;
    int wy = n / WIN, wx = n - (n / WIN) * WIN;
    rmap[p] = ((gy * WIN + wy + 4) % IMG) * IMG + (gx * WIN + wx + 4) % IMG;
  }
}

// ---------------- weights -> bf16 (once) ----------------
__global__ void k_wcvt(const float* __restrict__ wqkv, const float* __restrict__ wproj,
                       ushort* __restrict__ wqb, ushort* __restrict__ wpb) {
  int i = blockIdx.x * 256 + threadIdx.x;
  const int nq = 1152 * DIM / 8;
  const int np = DIM * DIM / 8;
  if (i < nq) {
    f4 a = *(const f4*)&wqkv[i * 8];
    f4 b = *(const f4*)&wqkv[i * 8 + 4];
    us8 u; u[0]=tob(a[0]);u[1]=tob(a[1]);u[2]=tob(a[2]);u[3]=tob(a[3]);
    u[4]=tob(b[0]);u[5]=tob(b[1]);u[6]=tob(b[2]);u[7]=tob(b[3]);
    *(us8*)&wqb[i * 8] = u;
  } else if (i < nq + np) {
    int j = i - nq;
    f4 a = *(const f4*)&wproj[j * 8];
    f4 b = *(const f4*)&wproj[j * 8 + 4];
    us8 u; u[0]=tob(a[0]);u[1]=tob(a[1]);u[2]=tob(a[2]);u[3]=tob(a[3]);
    u[4]=tob(b[0]);u[5]=tob(b[1]);u[6]=tob(b[2]);u[7]=tob(b[3]);
    *(us8*)&wpb[j * 8] = u;
  }
}

// ---------------- x -> xw[b][p'][c] bf16, window-ordered, roll folded -------
__global__ __launch_bounds__(256) void k_xw(const float* __restrict__ x,
                                            const int* __restrict__ rmap,
                                            ushort* __restrict__ xw) {
  int gid = blockIdx.x * 256 + threadIdx.x;   // 16*3136 exact
  int b = gid / NPF, p = gid - (gid / NPF) * NPF;
  int sp = rmap[p];
  const float* xs = x + (size_t)b * DIM * NPF + sp;
  ushort* xd = xw + ((size_t)b * NPF + p) * DIM;
  for (int c0 = 0; c0 < DIM; c0 += 8) {
    us8 u;
#pragma unroll
    for (int i = 0; i < 8; ++i) u[i] = tob(xs[(size_t)(c0 + i) * NPF]);
    *(us8*)&xd[c0] = u;
  }
}

// ================= FAST PATH (pixel-major) =================

// qkv_pm[b][p'][o]  = W . Xw  — grid 3600 XCD-swizzled, o fastest
__global__ __launch_bounds__(256) void k_qkv_pm(const ushort* __restrict__ xw,
                                                const ushort* __restrict__ wqb,
                                                ushort* __restrict__ qkv) {
  __shared__ __align__(16) ushort sA[2][128 * 40];
  __shared__ __align__(16) ushort sB[2][128 * 40];
  int t   = threadIdx.x;
  int bid = blockIdx.x;
  int swz = (bid & 7) * 450 + (bid >> 3);
  int o0  = (swz % 9) * 128;
  int pb  = swz / 9;
  int p0  = (pb % 25) * 128;
  int b   = pb / 25;

  int lane = t & 63, w = t >> 6;
  int wm = w >> 1, wn = w & 1;
  int l15 = lane & 15, l4 = lane >> 4;

  int row = t & 127, sh = (t >> 7) * 16;
  const ushort* apt = wqb + (size_t)(o0 + row) * DIM;
  int prow = p0 + row; if (prow >= NPF) prow = NPF - 1;
  const ushort* bpt = xw + ((size_t)b * NPF + prow) * DIM;

  f32x4 acc[4][4] = {};

  *(us8*)&sA[0][row * 40 + sh]     = *(const us8*)&apt[sh];
  *(us8*)&sA[0][row * 40 + sh + 8] = *(const us8*)&apt[sh + 8];
  *(us8*)&sB[0][row * 40 + sh]     = *(const us8*)&bpt[sh];
  *(us8*)&sB[0][row * 40 + sh + 8] = *(const us8*)&bpt[sh + 8];

  for (int ks = 0; ks < 12; ++ks) {
    __syncthreads();
    int cur = ks & 1;
    us8 a0, a1, b0, b1;
    if (ks < 11) {
      int k0 = (ks + 1) * 32;
      a0 = *(const us8*)&apt[k0 + sh]; a1 = *(const us8*)&apt[k0 + sh + 8];
      b0 = *(const us8*)&bpt[k0 + sh]; b1 = *(const us8*)&bpt[k0 + sh + 8];
    }
    short8 af[4], bfr[4];
#pragma unroll
    for (int mi = 0; mi < 4; ++mi)
      af[mi] = *(const short8*)&sA[cur][(wm * 64 + mi * 16 + l15) * 40 + l4 * 8];
#pragma unroll
    for (int ni = 0; ni < 4; ++ni)
      bfr[ni] = *(const short8*)&sB[cur][(wn * 64 + ni * 16 + l15) * 40 + l4 * 8];
#pragma unroll
    for (int mi = 0; mi < 4; ++mi)
#pragma unroll
      for (int ni = 0; ni < 4; ++ni)
        acc[mi][ni] = MFMA(af[mi], bfr[ni], acc[mi][ni], 0, 0, 0);
    if (ks < 11) {
      int nxt = cur ^ 1;
      *(us8*)&sA[nxt][row * 40 + sh]     = a0;
      *(us8*)&sA[nxt][row * 40 + sh + 8] = a1;
      *(us8*)&sB[nxt][row * 40 + sh]     = b0;
      *(us8*)&sB[nxt][row * 40 + sh + 8] = b1;
    }
  }

#pragma unroll
  for (int mi = 0; mi < 4; ++mi)
#pragma unroll
    for (int ni = 0; ni < 4; ++ni) {
      int p = p0 + wn * 64 + ni * 16 + l15;
      if (p < NPF) {
        us4 u;
#pragma unroll
        for (int r = 0; r < 4; ++r) u[r] = tob(acc[mi][ni][r]);
        *(us4*)&qkv[((size_t)b * NPF + p) * 1152 + o0 + wm * 64 + mi * 16 + (l4 << 2)] = u;
      }
    }
}

// attention per (window, head): pm layout, direct us8 staging, in-reg softmax
__global__ __launch_bounds__(64) void k_attn_pm(ushort* __restrict__ qkv,
                                                const float* __restrict__ bias) {
  __shared__ __align__(16) ushort smem[8992];
  ushort* sq  = smem;          // [64][40]
  ushort* skt = smem + 2560;   // [64][40]
  ushort* svt = smem + 5120;   // [32][72]
  ushort* stg = smem + 7424;   // [49][32]
  ushort* pa  = smem;          // [64][72] overlays sq/skt

  int t = threadIdx.x;
  int bid = blockIdx.x;
  int swz = (bid & 7) * 1536 + (bid >> 3);   // 12288 = 8*1536
  int h = swz % HEADS, wb = swz / HEADS;
  int b = wb >> 6;
  int w49 = (wb & 63) * NPIX;
  ushort* qrow = qkv + ((size_t)b * NPF + w49) * 1152 + h * HD;

  for (int idx = t; idx < 32 * 23; idx += 64) {
    int d = idx / 23, mm = 49 + (idx - d * 23);
    svt[d * 72 + mm] = 0;
  }
  for (int idx = t; idx < NPIX * 4; idx += 64) {
    int n = idx >> 2, s = (idx & 3) * 8;
    *(us8*)&sq [n * 40 + s] = *(const us8*)&qrow[(size_t)n * 1152 + s];
    *(us8*)&skt[n * 40 + s] = *(const us8*)&qrow[(size_t)n * 1152 + DIM + s];
    *(us8*)&stg[n * 32 + s] = *(const us8*)&qrow[(size_t)n * 1152 + 2 * DIM + s];
  }
  __syncthreads();
  for (int idx = t; idx < HD * NPIX; idx += 64) {
    int d = idx / NPIX, m = idx - d * NPIX;
    svt[d * 72 + m] = stg[m * 32 + d];
  }
  __syncthreads();

  int l15 = t & 15, l4 = t >> 4;
  f32x4 acc[4][4] = {};
  {
    short8 af[4], bfr[4];
#pragma unroll
    for (int mi = 0; mi < 4; ++mi) af[mi]  = *(const short8*)&sq [(mi * 16 + l15) * 40 + l4 * 8];
#pragma unroll
    for (int ni = 0; ni < 4; ++ni) bfr[ni] = *(const short8*)&skt[(ni * 16 + l15) * 40 + l4 * 8];
#pragma unroll
    for (int mi = 0; mi < 4; ++mi)
#pragma unroll
      for (int ni = 0; ni < 4; ++ni)
        acc[mi][ni] = MFMA(af[mi], bfr[ni], acc[mi][ni], 0, 0, 0);
  }

  const float scale = 0.17677669529663687f;
  const float* bh = bias + h * NPIX * NPIX;
  float mx[16], sm[16];
#pragma unroll
  for (int mi = 0; mi < 4; ++mi)
#pragma unroll
    for (int r = 0; r < 4; ++r) {
      int n = mi * 16 + (l4 << 2) + r;
      float vmax = -3e38f;
#pragma unroll
      for (int ni = 0; ni < 4; ++ni) {
        int m = ni * 16 + l15;
        float s = (m < NPIX)
                    ? acc[mi][ni][r] * scale + ((n < NPIX) ? bh[n * NPIX + m] : 0.f)
                    : -3e38f;
        acc[mi][ni][r] = s;
        vmax = fmaxf(vmax, s);
      }
      mx[mi * 4 + r] = vmax;
    }
#pragma unroll
  for (int i = 1; i < 16; i <<= 1)
#pragma unroll
    for (int j = 0; j < 16; ++j) mx[j] = fmaxf(mx[j], __shfl_xor(mx[j], i));
#pragma unroll
  for (int mi = 0; mi < 4; ++mi)
#pragma unroll
    for (int r = 0; r < 4; ++r) {
      float s = 0.f;
#pragma unroll
      for (int ni = 0; ni < 4; ++ni) {
        float e = expf(acc[mi][ni][r] - mx[mi * 4 + r]);
        acc[mi][ni][r] = e;
        s += e;
      }
      sm[mi * 4 + r] = s;
    }
#pragma unroll
  for (int i = 1; i < 16; i <<= 1)
#pragma unroll
    for (int j = 0; j < 16; ++j) sm[j] += __shfl_xor(sm[j], i);

  __syncthreads();
#pragma unroll
  for (int mi = 0; mi < 4; ++mi)
#pragma unroll
    for (int r = 0; r < 4; ++r) {
      float ri = 1.f / sm[mi * 4 + r];
      int n = mi * 16 + (l4 << 2) + r;
#pragma unroll
      for (int ni = 0; ni < 4; ++ni)
        pa[n * 72 + ni * 16 + l15] = tob(acc[mi][ni][r] * ri);
    }
  __syncthreads();

  f32x4 yac[4][2] = {};
#pragma unroll
  for (int ks = 0; ks < 2; ++ks) {
    short8 pf[4], vf[2];
#pragma unroll
    for (int mi = 0; mi < 4; ++mi) pf[mi] = *(const short8*)&pa [(mi * 16 + l15) * 72 + ks * 32 + l4 * 8];
#pragma unroll
    for (int nd = 0; nd < 2; ++nd) vf[nd] = *(const short8*)&svt[(nd * 16 + l15) * 72 + ks * 32 + l4 * 8];
#pragma unroll
    for (int mi = 0; mi < 4; ++mi)
#pragma unroll
      for (int nd = 0; nd < 2; ++nd)
        yac[mi][nd] = MFMA(pf[mi], vf[nd], yac[mi][nd], 0, 0, 0);
  }
  // Y over own Q slice (rows w49.., chans h*32..) — disjoint across blocks
#pragma unroll
  for (int mi = 0; mi < 4; ++mi)
#pragma unroll
    for (int nd = 0; nd < 2; ++nd) {
      int nb = mi * 16 + (l4 << 2);
      int d = nd * 16 + l15;
#pragma unroll
      for (int r = 0; r < 4; ++r)
        if (nb + r < NPIX) qrow[(size_t)(nb + r) * 1152 + d] = tob(yac[mi][nd][r]);
    }
}

// out[b][o][p] = Wp . Y   (Y = chans 0..383 of qkv_pm rows)
__global__ __launch_bounds__(256) void k_proj_pm(const ushort* __restrict__ qkv,
                                                 const ushort* __restrict__ wpb,
                                                 float* __restrict__ out) {
  __shared__ __align__(16) ushort sA[2][128 * 40];
  __shared__ __align__(16) ushort sB[2][128 * 40];
  __shared__ int srm[128];
  int t   = threadIdx.x;
  int bid = blockIdx.x;
  int swz = (bid & 7) * 150 + (bid >> 3);
  int o0  = (swz % 3) * 128;
  int pb  = swz / 3;
  int p0  = (pb % 25) * 128;
  int b   = pb / 25;
  if (t < 128) {
    int pg = p0 + t;
    if (pg >= NPF) pg = 0;
    int si = (pg / IMG + 53) % IMG, sj = (pg % IMG + 53) % IMG;
    srm[t] = ((si / WIN) * 8 + sj / WIN) * NPIX + (si % WIN) * WIN + (sj % WIN);
  }
  __syncthreads();

  int lane = t & 63, w = t >> 6;
  int wm = w >> 1, wn = w & 1;
  int l15 = lane & 15, l4 = lane >> 4;

  int row = t & 127, sh = (t >> 7) * 16;
  const ushort* apt = wpb + (size_t)(o0 + row) * DIM;
  const ushort* bpt = qkv + ((size_t)b * NPF + srm[row]) * 1152;

  f32x4 acc[4][4] = {};

  *(us8*)&sA[0][row * 40 + sh]     = *(const us8*)&apt[sh];
  *(us8*)&sA[0][row * 40 + sh + 8] = *(const us8*)&apt[sh + 8];
  *(us8*)&sB[0][row * 40 + sh]     = *(const us8*)&bpt[sh];
  *(us8*)&sB[0][row * 40 + sh + 8] = *(const us8*)&bpt[sh + 8];

  for (int ks = 0; ks < 12; ++ks) {
    __syncthreads();
    int cur = ks & 1;
    us8 a0, a1, b0, b1;
    if (ks < 11) {
      int k0 = (ks + 1) * 32;
      a0 = *(const us8*)&apt[k0 + sh]; a1 = *(const us8*)&apt[k0 + sh + 8];
      b0 = *(const us8*)&bpt[k0 + sh]; b1 = *(const us8*)&bpt[k0 + sh + 8];
    }
    short8 af[4], bfr[4];
#pragma unroll
    for (int mi = 0; mi < 4; ++mi)
      af[mi] = *(const short8*)&sA[cur][(wm * 64 + mi * 16 + l15) * 40 + l4 * 8];
#pragma unroll
    for (int ni = 0; ni < 4; ++ni)
      bfr[ni] = *(const short8*)&sB[cur][(wn * 64 + ni * 16 + l15) * 40 + l4 * 8];
#pragma unroll
    for (int mi = 0; mi < 4; ++mi)
#pragma unroll
      for (int ni = 0; ni < 4; ++ni)
        acc[mi][ni] = MFMA(af[mi], bfr[ni], acc[mi][ni], 0, 0, 0);
    if (ks < 11) {
      int nxt = cur ^ 1;
      *(us8*)&sA[nxt][row * 40 + sh]     = a0;
      *(us8*)&sA[nxt][row * 40 + sh + 8] = a1;
      *(us8*)&sB[nxt][row * 40 + sh]     = b0;
      *(us8*)&sB[nxt][row * 40 + sh + 8] = b1;
    }
  }

  for (int mi = 0; mi < 4; ++mi)
    for (int ni = 0; ni < 4; ++ni)
      for (int r = 0; r < 4; ++r) {
        int o = o0 + wm * 64 + mi * 16 + (l4 << 2) + r;
        int p = p0 + wn * 64 + ni * 16 + l15;
        if (p < NPF)
          out[((size_t)b * DIM + o) * NPF + p] = acc[mi][ni][r];
      }
}

// ================= FALLBACK (round-10 verbatim, channel-major) =================
__global__ __launch_bounds__(256) void k_qkv_cm(const float* __restrict__ x,
                                                const float* __restrict__ wqkv,
                                                const int* __restrict__ rmap,
                                                ushort* __restrict__ qkv) {
  __shared__ __align__(16) ushort sA[2][128 * 40];
  __shared__ __align__(16) ushort sB[2][128 * 40];
  __shared__ int srm[128];
  int t   = threadIdx.x;
  int bid = blockIdx.x;
  int swz = (bid & 7) * 450 + (bid >> 3);
  int o0  = (swz % 9) * 128;
  int pb  = swz / 9;
  int p0  = (pb % 25) * 128;
  int b   = pb / 25;
  if (t < 128) { int pg = p0 + t; srm[t] = rmap[(pg < NPF) ? pg : (NPF - 1)]; }
  __syncthreads();
  int lane = t & 63, w = t >> 6;
  int wm = w >> 1, wn = w & 1;
  int l15 = lane & 15, l4 = lane >> 4;
  int k4 = (t & 7) * 4, ar = t >> 3;
  int bp = t & 127, bc = (t >> 7) << 4;
  const float* xb = x + (size_t)b * DIM * NPF;
  f32x4 acc[4][4] = {};
  {
#pragma unroll
    for (int i = 0; i < 4; ++i) {
      int row = ar + 32 * i;
      f4 v = *(const f4*)&wqkv[(size_t)(o0 + row) * DIM + k4];
      us4 u; u[0] = tob(v[0]); u[1] = tob(v[1]); u[2] = tob(v[2]); u[3] = tob(v[3]);
      *(us4*)&sA[0][row * 40 + k4] = u;
    }
    int sp = srm[bp];
    us8 u0, u1;
#pragma unroll
    for (int i = 0; i < 8; ++i) u0[i] = tob(xb[(size_t)(bc + i) * NPF + sp]);
#pragma unroll
    for (int i = 0; i < 8; ++i) u1[i] = tob(xb[(size_t)(bc + 8 + i) * NPF + sp]);
    *(us8*)&sB[0][bp * 40 + bc] = u0;
    *(us8*)&sB[0][bp * 40 + bc + 8] = u1;
  }
  for (int ks = 0; ks < 12; ++ks) {
    __syncthreads();
    int cur = ks & 1;
    f4 aw[4]; float bw[16];
    if (ks < 11) {
      int k0 = (ks + 1) * 32;
#pragma unroll
      for (int i = 0; i < 4; ++i)
        aw[i] = *(const f4*)&wqkv[(size_t)(o0 + ar + 32 * i) * DIM + k0 + k4];
      int sp = srm[bp];
#pragma unroll
      for (int i = 0; i < 16; ++i)
        bw[i] = xb[(size_t)(k0 + bc + i) * NPF + sp];
    }
    short8 af[4], bfr[4];
#pragma unroll
    for (int mi = 0; mi < 4; ++mi)
      af[mi] = *(const short8*)&sA[cur][(wm * 64 + mi * 16 + l15) * 40 + l4 * 8];
#pragma unroll
    for (int ni = 0; ni < 4; ++ni)
      bfr[ni] = *(const short8*)&sB[cur][(wn * 64 + ni * 16 + l15) * 40 + l4 * 8];
#pragma unroll
    for (int mi = 0; mi < 4; ++mi)
#pragma unroll
      for (int ni = 0; ni < 4; ++ni)
        acc[mi][ni] = MFMA(af[mi], bfr[ni], acc[mi][ni], 0, 0, 0);
    if (ks < 11) {
      int nxt = cur ^ 1;
#pragma unroll
      for (int i = 0; i < 4; ++i) {
        us4 u; u[0] = tob(aw[i][0]); u[1] = tob(aw[i][1]); u[2] = tob(aw[i][2]); u[3] = tob(aw[i][3]);
        *(us4*)&sA[nxt][(ar + 32 * i) * 40 + k4] = u;
      }
      us8 u0, u1;
#pragma unroll
      for (int i = 0; i < 8; ++i) u0[i] = tob(bw[i]);
#pragma unroll
      for (int i = 0; i < 8; ++i) u1[i] = tob(bw[8 + i]);
      *(us8*)&sB[nxt][bp * 40 + bc] = u0;
      *(us8*)&sB[nxt][bp * 40 + bc + 8] = u1;
    }
  }
  for (int mi = 0; mi < 4; ++mi)
    for (int ni = 0; ni < 4; ++ni)
      for (int r = 0; r < 4; ++r) {
        int o = o0 + wm * 64 + mi * 16 + (l4 << 2) + r;
        int p = p0 + wn * 64 + ni * 16 + l15;
        if (p < NPF)
          qkv[((size_t)b * 1152 + o) * NPF + p] = tob(acc[mi][ni][r]);
      }
}

__global__ __launch_bounds__(64) void k_attn_cm(ushort* __restrict__ qkv,
                                                const float* __restrict__ bias) {
  __shared__ __align__(16) ushort smem[8992];
  ushort* sq  = smem;
  ushort* skt = smem + 2560;
  ushort* svt = smem + 5120;
  ushort* stg = smem + 7424;
  ushort* pa  = smem;
  int t = threadIdx.x;
  int bid = blockIdx.x;
  int h = bid % HEADS, wb = bid / HEADS;
  int b = wb >> 6;
  int w49 = (wb & 63) * NPIX;
  size_t qb = ((size_t)b * 1152 + h * HD) * NPF;
  size_t kb = qb + (size_t)DIM * NPF;
  size_t vb = qb + (size_t)(2 * DIM) * NPF;
  for (int idx = t; idx < 32 * 23; idx += 64) {
    int d = idx / 23, mm = 49 + (idx - d * 23);
    svt[d * 72 + mm] = 0;
  }
  for (int idx = t; idx < HD * NPIX; idx += 64) stg[idx] = qkv[qb + (size_t)(idx / NPIX) * NPF + w49 + (idx % NPIX)];
  __syncthreads();
  for (int idx = t; idx < HD * NPIX; idx += 64) {
    int d = idx / NPIX, n = idx - d * NPIX;
    sq[n * 40 + d] = stg[idx];
  }
  for (int idx = t; idx < HD * NPIX; idx += 64) {
    int d = idx / NPIX, m = idx - d * NPIX;
    svt[d * 72 + m] = qkv[vb + (size_t)d * NPF + w49 + m];
  }
  __syncthreads();
  for (int idx = t; idx < HD * NPIX; idx += 64) stg[idx] = qkv[kb + (size_t)(idx / NPIX) * NPF + w49 + (idx % NPIX)];
  __syncthreads();
  for (int idx = t; idx < HD * NPIX; idx += 64) {
    int d = idx / NPIX, m = idx - d * NPIX;
    skt[m * 40 + d] = stg[idx];
  }
  __syncthreads();
  int l15 = t & 15, l4 = t >> 4;
  f32x4 acc[4][4] = {};
  {
    short8 af[4], bfr[4];
#pragma unroll
    for (int mi = 0; mi < 4; ++mi) af[mi]  = *(const short8*)&sq [(mi * 16 + l15) * 40 + l4 * 8];
#pragma unroll
    for (int ni = 0; ni < 4; ++ni) bfr[ni] = *(const short8*)&skt[(ni * 16 + l15) * 40 + l4 * 8];
#pragma unroll
    for (int mi = 0; mi < 4; ++mi)
#pragma unroll
      for (int ni = 0; ni < 4; ++ni)
        acc[mi][ni] = MFMA(af[mi], bfr[ni], acc[mi][ni], 0, 0, 0);
  }
  const float scale = 0.17677669529663687f;
  const float* bh = bias + h * NPIX * NPIX;
  float mx[16], sm[16];
#pragma unroll
  for (int mi = 0; mi < 4; ++mi)
#pragma unroll
    for (int r = 0; r < 4; ++r) {
      int n = mi * 16 + (l4 << 2) + r;
      float vmax = -3e38f;
#pragma unroll
      for (int ni = 0; ni < 4; ++ni) {
        int m = ni * 16 + l15;
        float s = (m < NPIX)
                    ? acc[mi][ni][r] * scale + ((n < NPIX) ? bh[n * NPIX + m] : 0.f)
                    : -3e38f;
        acc[mi][ni][r] = s;
        vmax = fmaxf(vmax, s);
      }
      mx[mi * 4 + r] = vmax;
    }
#pragma unroll
  for (int i = 1; i < 16; i <<= 1)
#pragma unroll
    for (int j = 0; j < 16; ++j) mx[j] = fmaxf(mx[j], __shfl_xor(mx[j], i));
#pragma unroll
  for (int mi = 0; mi < 4; ++mi)
#pragma unroll
    for (int r = 0; r < 4; ++r) {
      float s = 0.f;
#pragma unroll
      for (int ni = 0; ni < 4; ++ni) {
        float e = expf(acc[mi][ni][r] - mx[mi * 4 + r]);
        acc[mi][ni][r] = e;
        s += e;
      }
      sm[mi * 4 + r] = s;
    }
#pragma unroll
  for (int i = 1; i < 16; i <<= 1)
#pragma unroll
    for (int j = 0; j < 16; ++j) sm[j] += __shfl_xor(sm[j], i);
  __syncthreads();
#pragma unroll
  for (int mi = 0; mi < 4; ++mi)
#pragma unroll
    for (int r = 0; r < 4; ++r) {
      float ri = 1.f / sm[mi * 4 + r];
      int n = mi * 16 + (l4 << 2) + r;
#pragma unroll
      for (int ni = 0; ni < 4; ++ni)
        pa[n * 72 + ni * 16 + l15] = tob(acc[mi][ni][r] * ri);
    }
  __syncthreads();
  f32x4 yac[4][2] = {};
#pragma unroll
  for (int ks = 0; ks < 2; ++ks) {
    short8 pf[4], vf[2];
#pragma unroll
    for (int mi = 0; mi < 4; ++mi) pf[mi] = *(const short8*)&pa [(mi * 16 + l15) * 72 + ks * 32 + l4 * 8];
#pragma unroll
    for (int nd = 0; nd < 2; ++nd) vf[nd] = *(const short8*)&svt[(nd * 16 + l15) * 72 + ks * 32 + l4 * 8];
#pragma unroll
    for (int mi = 0; mi < 4; ++mi)
#pragma unroll
      for (int nd = 0; nd < 2; ++nd)
        yac[mi][nd] = MFMA(pf[mi], vf[nd], yac[mi][nd], 0, 0, 0);
  }
#pragma unroll
  for (int mi = 0; mi < 4; ++mi)
#pragma unroll
    for (int nd = 0; nd < 2; ++nd) {
      int nb = mi * 16 + (l4 << 2);
      int d = nd * 16 + l15;
      size_t ga = qb + (size_t)d * NPF + w49 + nb;
#pragma unroll
      for (int r = 0; r < 4; ++r)
        if (nb + r < NPIX) qkv[ga + r] = tob(yac[mi][nd][r]);
    }
}

__global__ __launch_bounds__(256) void k_proj_cm(const ushort* __restrict__ yq,
                                                 const float* __restrict__ wproj,
                                                 float* __restrict__ out) {
  __shared__ __align__(16) ushort sA[2][128 * 40];
  __shared__ __align__(16) ushort sB[2][128 * 40];
  __shared__ int srm[128];
  int t   = threadIdx.x;
  int bid = blockIdx.x;
  int swz = (bid & 7) * 150 + (bid >> 3);
  int o0  = (swz % 3) * 128;
  int pb  = swz / 3;
  int p0  = (pb % 25) * 128;
  int b   = pb / 25;
  if (t < 128) {
    int pg = p0 + t;
    if (pg >= NPF) pg = 0;
    int si = (pg / IMG + 53) % IMG, sj = (pg % IMG + 53) % IMG;
    srm[t] = ((si / WIN) * 8 + sj / WIN) * NPIX + (si % WIN) * WIN + (sj % WIN);
  }
  __syncthreads();
  int lane = t & 63, w = t >> 6;
  int wm = w >> 1, wn = w & 1;
  int l15 = lane & 15, l4 = lane >> 4;
  int k4 = (t & 7) * 4, ar = t >> 3;
  int bp = t & 127, bc = (t >> 7) << 4;
  const ushort* yb = yq + (size_t)b * 1152 * NPF;
  f32x4 acc[4][4] = {};
  {
#pragma unroll
    for (int i = 0; i < 4; ++i) {
      int row = ar + 32 * i;
      f4 v = *(const f4*)&wproj[(size_t)(o0 + row) * DIM + k4];
      us4 u; u[0] = tob(v[0]); u[1] = tob(v[1]); u[2] = tob(v[2]); u[3] = tob(v[3]);
      *(us4*)&sA[0][row * 40 + k4] = u;
    }
    int sp = srm[bp];
    us8 u0, u1;
#pragma unroll
    for (int i = 0; i < 8; ++i) u0[i] = yb[(size_t)(bc + i) * NPF + sp];
#pragma unroll
    for (int i = 0; i < 8; ++i) u1[i] = yb[(size_t)(bc + 8 + i) * NPF + sp];
    *(us8*)&sB[0][bp * 40 + bc] = u0;
    *(us8*)&sB[0][bp * 40 + bc + 8] = u1;
  }
  for (int ks = 0; ks < 12; ++ks) {
    __syncthreads();
    int cur = ks & 1;
    f4 aw[4]; ushort bw[16];
    if (ks < 11) {
      int k0 = (ks + 1) * 32;
#pragma unroll
      for (int i = 0; i < 4; ++i)
        aw[i] = *(const f4*)&wproj[(size_t)(o0 + ar + 32 * i) * DIM + k0 + k4];
      int sp = srm[bp];
#pragma unroll
      for (int i = 0; i < 16; ++i)
        bw[i] = yb[(size_t)(k0 + bc + i) * NPF + sp];
    }
    short8 af[4], bfr[4];
#pragma unroll
    for (int mi = 0; mi < 4; ++mi)
      af[mi] = *(const short8*)&sA[cur][(wm * 64 + mi * 16 + l15) * 40 + l4 * 8];
#pragma unroll
    for (int ni = 0; ni < 4; ++ni)
      bfr[ni] = *(const short8*)&sB[cur][(wn * 64 + ni * 16 + l15) * 40 + l4 * 8];
#pragma unroll
    for (int mi = 0; mi < 4; ++mi)
#pragma unroll
      for (int ni = 0; ni < 4; ++ni)
        acc[mi][ni] = MFMA(af[mi], bfr[ni], acc[mi][ni], 0, 0, 0);
    if (ks < 11) {
      int nxt = cur ^ 1;
#pragma unroll
      for (int i = 0; i < 4; ++i) {
        us4 u; u[0] = tob(aw[i][0]); u[1] = tob(aw[i][1]); u[2] = tob(aw[i][2]); u[3] = tob(aw[i][3]);
        *(us4*)&sA[nxt][(ar + 32 * i) * 40 + k4] = u;
      }
      us8 u0, u1;
#pragma unroll
      for (int i = 0; i < 8; ++i) u0[i] = bw[i];
#pragma unroll
      for (int i = 0; i < 8; ++i) u1[i] = bw[8 + i];
      *(us8*)&sB[nxt][bp * 40 + bc] = u0;
      *(us8*)&sB[nxt][bp * 40 + bc + 8] = u1;
    }
  }
  for (int mi = 0; mi < 4; ++mi)
    for (int ni = 0; ni < 4; ++ni)
      for (int r = 0; r < 4; ++r) {
        int o = o0 + wm * 64 + mi * 16 + (l4 << 2) + r;
        int p = p0 + wn * 64 + ni * 16 + l15;
        if (p < NPF)
          out[((size_t)b * DIM + o) * NPF + p] = acc[mi][ni][r];
      }
}

extern "C" void kernel_launch(void* const* d_in, const int* in_sizes, int n_in,
                              void* d_out, int out_size, void* d_ws, size_t ws_size,
                              hipStream_t stream) {
  const float* x     = (const float*)d_in[0];
  const float* wqkv  = (const float*)d_in[1];
  const float* wproj = (const float*)d_in[2];
  const float* cpb   = (const float*)d_in[3];
  float* out = (float*)d_out;

  char* ws = (char*)d_ws;
  float* bias = (float*)ws;                    // 115248 B
  int*   rmap = (int*)(ws + 115712);           // 12544 B -> 131072

  hipLaunchKernelGGL(k_bias, dim3(113), dim3(256), 0, stream, cpb, bias);
  hipLaunchKernelGGL(k_rmap, dim3(13), dim3(256), 0, stream, rmap);

  const size_t QKV_B = (size_t)16 * 1152 * NPF * 2;       // 115,605,504
  const size_t XW_B  = (size_t)16 * NPF * DIM * 2;        // 38,535,168
  const size_t need  = 1310720 + QKV_B + XW_B;            // 155,451,392

  if (ws_size >= need) {
    ushort* wqb = (ushort*)(ws + 131072);                 // 884736 B
    ushort* wpb = (ushort*)(ws + 1015808);                // 294912 B -> 1310720
    ushort* qkv = (ushort*)(ws + 1310720);
    ushort* xw  = (ushort*)(ws + 1310720 + QKV_B);
    hipLaunchKernelGGL(k_wcvt, dim3(288), dim3(256), 0, stream, wqkv, wproj, wqb, wpb);
    hipLaunchKernelGGL(k_xw, dim3(196), dim3(256), 0, stream, x, rmap, xw);
    hipLaunchKernelGGL(k_qkv_pm, dim3(3600), dim3(256), 0, stream, xw, wqb, qkv);
    hipLaunchKernelGGL(k_attn_pm, dim3(NWIN * HEADS), dim3(64), 0, stream, qkv, bias);
    hipLaunchKernelGGL(k_proj_pm, dim3(1200), dim3(256), 0, stream, qkv, wpb, out);
  } else {
    ushort* qkv = (ushort*)(ws + 131072);
    hipLaunchKernelGGL(k_qkv_cm, dim3(3600), dim3(256), 0, stream, x, wqkv, rmap, qkv);
    hipLaunchKernelGGL(k_attn_cm, dim3(NWIN * HEADS), dim3(64), 0, stream, qkv, bias);
    hipLaunchKernelGGL(k_proj_cm, dim3(1200), dim3(256), 0, stream, qkv, wproj, out);
  }
}

// Round 12
// 309.368 us; speedup vs baseline: 1.4370x; 1.0395x over previous
//
#include <hip/hip_runtime.h>
#include <hip/hip_bf16.h>
#include <math.h>

#define DIM   384
#define HEADS 12
#define HD    32
#define WIN   7
#define NPIX  49
#define IMG   56
#define NPF   3136   // IMG*IMG
#define NWIN  1024

typedef __attribute__((ext_vector_type(8))) short short8;
typedef __attribute__((ext_vector_type(4))) float f32x4;
typedef __attribute__((ext_vector_type(4))) float f4;
typedef __attribute__((ext_vector_type(4))) unsigned short us4;
typedef __attribute__((ext_vector_type(8))) unsigned short us8;
#define MFMA __builtin_amdgcn_mfma_f32_16x16x32_bf16

__device__ inline ushort tob(float f) {
  unsigned u; __builtin_memcpy(&u, &f, 4);
  u += 0x7fffu + ((u >> 16) & 1u);
  return (ushort)(u >> 16);
}

// ---------------- bias table ----------------
__global__ void k_bias(const float* __restrict__ cpb, float* __restrict__ bias) {
  int idx = blockIdx.x * 256 + threadIdx.x;
  if (idx >= HEADS * NPIX * NPIX) return;
  int m = idx % NPIX;
  int n = (idx / NPIX) % NPIX;
  int h = idx / (NPIX * NPIX);
  int sy = (n / WIN - m / WIN) + (WIN - 1);
  int sx = (n % WIN - m % WIN) + (WIN - 1);
  const double inv_log_beta = 1.0 / log(1.3);
  double fy = (sy == 0 ? 0.0 : log1p((double)sy) * inv_log_beta) + 6.0;
  double fx = (sx == 0 ? 0.0 : log1p((double)sx) * inv_log_beta) + 6.0;
  fy = fmin(12.0, fmax(0.0, fy));
  fx = fmin(12.0, fmax(0.0, fx));
  int ridx = (int)(fy * 13.0 + fx);
  bias[idx] = cpb[ridx * HEADS + h];
}

__global__ void k_rmap(int* __restrict__ rmap) {
  int p = blockIdx.x * 256 + threadIdx.x;
  if (p < NPF) {
    int wb = p / NPIX, n = p - (p / NPIX) * NPIX;
    int gy = wb >> 3, gx = wb & 7;
    int wy = n / WIN, wx = n - (n / WIN) * WIN;
    rmap[p] = ((gy * WIN + wy + 4) % IMG) * IMG + (gx * WIN + wx + 4) % IMG;
  }
}

// ---------------- weights -> bf16 (once) ----------------
__global__ void k_wcvt(const float* __restrict__ wqkv, const float* __restrict__ wproj,
                       ushort* __restrict__ wqb, ushort* __restrict__ wpb) {
  int i = blockIdx.x * 256 + threadIdx.x;
  const int nq = 1152 * DIM / 8;
  const int np = DIM * DIM / 8;
  if (i < nq) {
    f4 a = *(const f4*)&wqkv[i * 8];
    f4 b = *(const f4*)&wqkv[i * 8 + 4];
    us8 u; u[0]=tob(a[0]);u[1]=tob(a[1]);u[2]=tob(a[2]);u[3]=tob(a[3]);
    u[4]=tob(b[0]);u[5]=tob(b[1]);u[6]=tob(b[2]);u[7]=tob(b[3]);
    *(us8*)&wqb[i * 8] = u;
  } else if (i < nq + np) {
    int j = i - nq;
    f4 a = *(const f4*)&wproj[j * 8];
    f4 b = *(const f4*)&wproj[j * 8 + 4];
    us8 u; u[0]=tob(a[0]);u[1]=tob(a[1]);u[2]=tob(a[2]);u[3]=tob(a[3]);
    u[4]=tob(b[0]);u[5]=tob(b[1]);u[6]=tob(b[2]);u[7]=tob(b[3]);
    *(us8*)&wpb[j * 8] = u;
  }
}

// ---------------- x -> xw[b][p'][c] bf16, window-ordered, roll folded -------
__global__ __launch_bounds__(256) void k_xw(const float* __restrict__ x,
                                            const int* __restrict__ rmap,
                                            ushort* __restrict__ xw) {
  int gid = blockIdx.x * 256 + threadIdx.x;   // 16*3136 exact
  int b = gid / NPF, p = gid - (gid / NPF) * NPF;
  int sp = rmap[p];
  const float* xs = x + (size_t)b * DIM * NPF + sp;
  ushort* xd = xw + ((size_t)b * NPF + p) * DIM;
  for (int c0 = 0; c0 < DIM; c0 += 8) {
    us8 u;
#pragma unroll
    for (int i = 0; i < 8; ++i) u[i] = tob(xs[(size_t)(c0 + i) * NPF]);
    *(us8*)&xd[c0] = u;
  }
}

// ================= FAST PATH (pixel-major) =================

// qkv_pm[b][p'][o]  = W . Xw  — block tile 128(o) x 256(p), wave tile 64x128
// grid 1872 = 9 x 13 x 16, XCD-swizzled (1872 = 8*234), o fastest
__global__ __launch_bounds__(256) void k_qkv_pm(const ushort* __restrict__ xw,
                                                const ushort* __restrict__ wqb,
                                                ushort* __restrict__ qkv) {
  __shared__ __align__(16) ushort sA[2][128 * 40];
  __shared__ __align__(16) ushort sB[2][256 * 40];
  int t   = threadIdx.x;
  int bid = blockIdx.x;
  int swz = (bid & 7) * 234 + (bid >> 3);   // bijective
  int o0  = (swz % 9) * 128;
  int pbt = swz / 9;
  int p0  = (pbt % 13) * 256;
  int b   = pbt / 13;

  int lane = t & 63, w = t >> 6;
  int wm = w >> 1, wn = w & 1;
  int l15 = lane & 15, l4 = lane >> 4;

  // A stage: 2 threads/row, 16 ch each
  int arow = t & 127, ash = (t >> 7) * 16;
  const ushort* apt = wqb + (size_t)(o0 + arow) * DIM + ash;
  // B stage: 1 thread/row, 32 ch
  int brow = t;
  int prow = p0 + brow; if (prow >= NPF) prow = NPF - 1;
  const ushort* bpt = xw + ((size_t)b * NPF + prow) * DIM;

  f32x4 acc[4][8] = {};

  *(us8*)&sA[0][arow * 40 + ash]     = *(const us8*)&apt[0];
  *(us8*)&sA[0][arow * 40 + ash + 8] = *(const us8*)&apt[8];
#pragma unroll
  for (int j = 0; j < 4; ++j)
    *(us8*)&sB[0][brow * 40 + j * 8] = *(const us8*)&bpt[j * 8];

  for (int ks = 0; ks < 12; ++ks) {
    __syncthreads();
    int cur = ks & 1;
    us8 a0, a1, b0, b1, b2, b3;
    if (ks < 11) {
      int k0 = (ks + 1) * 32;
      a0 = *(const us8*)&apt[k0];
      a1 = *(const us8*)&apt[k0 + 8];
      b0 = *(const us8*)&bpt[k0];
      b1 = *(const us8*)&bpt[k0 + 8];
      b2 = *(const us8*)&bpt[k0 + 16];
      b3 = *(const us8*)&bpt[k0 + 24];
    }
    short8 af[4], bfr[8];
#pragma unroll
    for (int mi = 0; mi < 4; ++mi)
      af[mi] = *(const short8*)&sA[cur][(wm * 64 + mi * 16 + l15) * 40 + l4 * 8];
#pragma unroll
    for (int ni = 0; ni < 8; ++ni)
      bfr[ni] = *(const short8*)&sB[cur][(wn * 128 + ni * 16 + l15) * 40 + l4 * 8];
#pragma unroll
    for (int mi = 0; mi < 4; ++mi)
#pragma unroll
      for (int ni = 0; ni < 8; ++ni)
        acc[mi][ni] = MFMA(af[mi], bfr[ni], acc[mi][ni], 0, 0, 0);
    if (ks < 11) {
      int nxt = cur ^ 1;
      *(us8*)&sA[nxt][arow * 40 + ash]     = a0;
      *(us8*)&sA[nxt][arow * 40 + ash + 8] = a1;
      *(us8*)&sB[nxt][brow * 40]      = b0;
      *(us8*)&sB[nxt][brow * 40 + 8]  = b1;
      *(us8*)&sB[nxt][brow * 40 + 16] = b2;
      *(us8*)&sB[nxt][brow * 40 + 24] = b3;
    }
  }

#pragma unroll
  for (int mi = 0; mi < 4; ++mi)
#pragma unroll
    for (int ni = 0; ni < 8; ++ni) {
      int p = p0 + wn * 128 + ni * 16 + l15;
      if (p < NPF) {
        us4 u;
#pragma unroll
        for (int r = 0; r < 4; ++r) u[r] = tob(acc[mi][ni][r]);
        *(us4*)&qkv[((size_t)b * NPF + p) * 1152 + o0 + wm * 64 + mi * 16 + (l4 << 2)] = u;
      }
    }
}

// attention per (window, head): pm layout, direct us8 staging, in-reg softmax
__global__ __launch_bounds__(64) void k_attn_pm(ushort* __restrict__ qkv,
                                                const float* __restrict__ bias) {
  __shared__ __align__(16) ushort smem[8992];
  ushort* sq  = smem;          // [64][40]
  ushort* skt = smem + 2560;   // [64][40]
  ushort* svt = smem + 5120;   // [32][72]
  ushort* stg = smem + 7424;   // [49][32]
  ushort* pa  = smem;          // [64][72] overlays sq/skt

  int t = threadIdx.x;
  int bid = blockIdx.x;
  int swz = (bid & 7) * 1536 + (bid >> 3);   // 12288 = 8*1536
  int h = swz % HEADS, wb = swz / HEADS;
  int b = wb >> 6;
  int w49 = (wb & 63) * NPIX;
  ushort* qrow = qkv + ((size_t)b * NPF + w49) * 1152 + h * HD;

  for (int idx = t; idx < 32 * 23; idx += 64) {
    int d = idx / 23, mm = 49 + (idx - d * 23);
    svt[d * 72 + mm] = 0;
  }
  for (int idx = t; idx < NPIX * 4; idx += 64) {
    int n = idx >> 2, s = (idx & 3) * 8;
    *(us8*)&sq [n * 40 + s] = *(const us8*)&qrow[(size_t)n * 1152 + s];
    *(us8*)&skt[n * 40 + s] = *(const us8*)&qrow[(size_t)n * 1152 + DIM + s];
    *(us8*)&stg[n * 32 + s] = *(const us8*)&qrow[(size_t)n * 1152 + 2 * DIM + s];
  }
  __syncthreads();
  for (int idx = t; idx < HD * NPIX; idx += 64) {
    int d = idx / NPIX, m = idx - d * NPIX;
    svt[d * 72 + m] = stg[m * 32 + d];
  }
  __syncthreads();

  int l15 = t & 15, l4 = t >> 4;
  f32x4 acc[4][4] = {};
  {
    short8 af[4], bfr[4];
#pragma unroll
    for (int mi = 0; mi < 4; ++mi) af[mi]  = *(const short8*)&sq [(mi * 16 + l15) * 40 + l4 * 8];
#pragma unroll
    for (int ni = 0; ni < 4; ++ni) bfr[ni] = *(const short8*)&skt[(ni * 16 + l15) * 40 + l4 * 8];
#pragma unroll
    for (int mi = 0; mi < 4; ++mi)
#pragma unroll
      for (int ni = 0; ni < 4; ++ni)
        acc[mi][ni] = MFMA(af[mi], bfr[ni], acc[mi][ni], 0, 0, 0);
  }

  const float scale = 0.17677669529663687f;
  const float* bh = bias + h * NPIX * NPIX;
  float mx[16], sm[16];
#pragma unroll
  for (int mi = 0; mi < 4; ++mi)
#pragma unroll
    for (int r = 0; r < 4; ++r) {
      int n = mi * 16 + (l4 << 2) + r;
      float vmax = -3e38f;
#pragma unroll
      for (int ni = 0; ni < 4; ++ni) {
        int m = ni * 16 + l15;
        float s = (m < NPIX)
                    ? acc[mi][ni][r] * scale + ((n < NPIX) ? bh[n * NPIX + m] : 0.f)
                    : -3e38f;
        acc[mi][ni][r] = s;
        vmax = fmaxf(vmax, s);
      }
      mx[mi * 4 + r] = vmax;
    }
#pragma unroll
  for (int i = 1; i < 16; i <<= 1)
#pragma unroll
    for (int j = 0; j < 16; ++j) mx[j] = fmaxf(mx[j], __shfl_xor(mx[j], i));
#pragma unroll
  for (int mi = 0; mi < 4; ++mi)
#pragma unroll
    for (int r = 0; r < 4; ++r) {
      float s = 0.f;
#pragma unroll
      for (int ni = 0; ni < 4; ++ni) {
        float e = expf(acc[mi][ni][r] - mx[mi * 4 + r]);
        acc[mi][ni][r] = e;
        s += e;
      }
      sm[mi * 4 + r] = s;
    }
#pragma unroll
  for (int i = 1; i < 16; i <<= 1)
#pragma unroll
    for (int j = 0; j < 16; ++j) sm[j] += __shfl_xor(sm[j], i);

  __syncthreads();
#pragma unroll
  for (int mi = 0; mi < 4; ++mi)
#pragma unroll
    for (int r = 0; r < 4; ++r) {
      float ri = 1.f / sm[mi * 4 + r];
      int n = mi * 16 + (l4 << 2) + r;
#pragma unroll
      for (int ni = 0; ni < 4; ++ni)
        pa[n * 72 + ni * 16 + l15] = tob(acc[mi][ni][r] * ri);
    }
  __syncthreads();

  f32x4 yac[4][2] = {};
#pragma unroll
  for (int ks = 0; ks < 2; ++ks) {
    short8 pf[4], vf[2];
#pragma unroll
    for (int mi = 0; mi < 4; ++mi) pf[mi] = *(const short8*)&pa [(mi * 16 + l15) * 72 + ks * 32 + l4 * 8];
#pragma unroll
    for (int nd = 0; nd < 2; ++nd) vf[nd] = *(const short8*)&svt[(nd * 16 + l15) * 72 + ks * 32 + l4 * 8];
#pragma unroll
    for (int mi = 0; mi < 4; ++mi)
#pragma unroll
      for (int nd = 0; nd < 2; ++nd)
        yac[mi][nd] = MFMA(pf[mi], vf[nd], yac[mi][nd], 0, 0, 0);
  }
  // Y over own Q slice (rows w49.., chans h*32..) — disjoint across blocks
#pragma unroll
  for (int mi = 0; mi < 4; ++mi)
#pragma unroll
    for (int nd = 0; nd < 2; ++nd) {
      int nb = mi * 16 + (l4 << 2);
      int d = nd * 16 + l15;
#pragma unroll
      for (int r = 0; r < 4; ++r)
        if (nb + r < NPIX) qrow[(size_t)(nb + r) * 1152 + d] = tob(yac[mi][nd][r]);
    }
}

// out[b][o][p] = Wp . Y   (Y = chans 0..383 of qkv_pm rows)
__global__ __launch_bounds__(256) void k_proj_pm(const ushort* __restrict__ qkv,
                                                 const ushort* __restrict__ wpb,
                                                 float* __restrict__ out) {
  __shared__ __align__(16) ushort sA[2][128 * 40];
  __shared__ __align__(16) ushort sB[2][128 * 40];
  __shared__ int srm[128];
  int t   = threadIdx.x;
  int bid = blockIdx.x;
  int swz = (bid & 7) * 150 + (bid >> 3);
  int o0  = (swz % 3) * 128;
  int pb  = swz / 3;
  int p0  = (pb % 25) * 128;
  int b   = pb / 25;
  if (t < 128) {
    int pg = p0 + t;
    if (pg >= NPF) pg = 0;
    int si = (pg / IMG + 53) % IMG, sj = (pg % IMG + 53) % IMG;
    srm[t] = ((si / WIN) * 8 + sj / WIN) * NPIX + (si % WIN) * WIN + (sj % WIN);
  }
  __syncthreads();

  int lane = t & 63, w = t >> 6;
  int wm = w >> 1, wn = w & 1;
  int l15 = lane & 15, l4 = lane >> 4;

  int row = t & 127, sh = (t >> 7) * 16;
  const ushort* apt = wpb + (size_t)(o0 + row) * DIM;
  const ushort* bpt = qkv + ((size_t)b * NPF + srm[row]) * 1152;

  f32x4 acc[4][4] = {};

  *(us8*)&sA[0][row * 40 + sh]     = *(const us8*)&apt[sh];
  *(us8*)&sA[0][row * 40 + sh + 8] = *(const us8*)&apt[sh + 8];
  *(us8*)&sB[0][row * 40 + sh]     = *(const us8*)&bpt[sh];
  *(us8*)&sB[0][row * 40 + sh + 8] = *(const us8*)&bpt[sh + 8];

  for (int ks = 0; ks < 12; ++ks) {
    __syncthreads();
    int cur = ks & 1;
    us8 a0, a1, b0, b1;
    if (ks < 11) {
      int k0 = (ks + 1) * 32;
      a0 = *(const us8*)&apt[k0 + sh]; a1 = *(const us8*)&apt[k0 + sh + 8];
      b0 = *(const us8*)&bpt[k0 + sh]; b1 = *(const us8*)&bpt[k0 + sh + 8];
    }
    short8 af[4], bfr[4];
#pragma unroll
    for (int mi = 0; mi < 4; ++mi)
      af[mi] = *(const short8*)&sA[cur][(wm * 64 + mi * 16 + l15) * 40 + l4 * 8];
#pragma unroll
    for (int ni = 0; ni < 4; ++ni)
      bfr[ni] = *(const short8*)&sB[cur][(wn * 64 + ni * 16 + l15) * 40 + l4 * 8];
#pragma unroll
    for (int mi = 0; mi < 4; ++mi)
#pragma unroll
      for (int ni = 0; ni < 4; ++ni)
        acc[mi][ni] = MFMA(af[mi], bfr[ni], acc[mi][ni], 0, 0, 0);
    if (ks < 11) {
      int nxt = cur ^ 1;
      *(us8*)&sA[nxt][row * 40 + sh]     = a0;
      *(us8*)&sA[nxt][row * 40 + sh + 8] = a1;
      *(us8*)&sB[nxt][row * 40 + sh]     = b0;
      *(us8*)&sB[nxt][row * 40 + sh + 8] = b1;
    }
  }

  for (int mi = 0; mi < 4; ++mi)
    for (int ni = 0; ni < 4; ++ni)
      for (int r = 0; r < 4; ++r) {
        int o = o0 + wm * 64 + mi * 16 + (l4 << 2) + r;
        int p = p0 + wn * 64 + ni * 16 + l15;
        if (p < NPF)
          out[((size_t)b * DIM + o) * NPF + p] = acc[mi][ni][r];
      }
}

// ================= FALLBACK (channel-major) =================
__global__ __launch_bounds__(256) void k_qkv_cm(const float* __restrict__ x,
                                                const float* __restrict__ wqkv,
                                                const int* __restrict__ rmap,
                                                ushort* __restrict__ qkv) {
  __shared__ __align__(16) ushort sA[2][128 * 40];
  __shared__ __align__(16) ushort sB[2][128 * 40];
  __shared__ int srm[128];
  int t   = threadIdx.x;
  int bid = blockIdx.x;
  int swz = (bid & 7) * 450 + (bid >> 3);
  int o0  = (swz % 9) * 128;
  int pb  = swz / 9;
  int p0  = (pb % 25) * 128;
  int b   = pb / 25;
  if (t < 128) { int pg = p0 + t; srm[t] = rmap[(pg < NPF) ? pg : (NPF - 1)]; }
  __syncthreads();
  int lane = t & 63, w = t >> 6;
  int wm = w >> 1, wn = w & 1;
  int l15 = lane & 15, l4 = lane >> 4;
  int k4 = (t & 7) * 4, ar = t >> 3;
  int bp = t & 127, bc = (t >> 7) << 4;
  const float* xb = x + (size_t)b * DIM * NPF;
  f32x4 acc[4][4] = {};
  {
#pragma unroll
    for (int i = 0; i < 4; ++i) {
      int row = ar + 32 * i;
      f4 v = *(const f4*)&wqkv[(size_t)(o0 + row) * DIM + k4];
      us4 u; u[0] = tob(v[0]); u[1] = tob(v[1]); u[2] = tob(v[2]); u[3] = tob(v[3]);
      *(us4*)&sA[0][row * 40 + k4] = u;
    }
    int sp = srm[bp];
    us8 u0, u1;
#pragma unroll
    for (int i = 0; i < 8; ++i) u0[i] = tob(xb[(size_t)(bc + i) * NPF + sp]);
#pragma unroll
    for (int i = 0; i < 8; ++i) u1[i] = tob(xb[(size_t)(bc + 8 + i) * NPF + sp]);
    *(us8*)&sB[0][bp * 40 + bc] = u0;
    *(us8*)&sB[0][bp * 40 + bc + 8] = u1;
  }
  for (int ks = 0; ks < 12; ++ks) {
    __syncthreads();
    int cur = ks & 1;
    f4 aw[4]; float bw[16];
    if (ks < 11) {
      int k0 = (ks + 1) * 32;
#pragma unroll
      for (int i = 0; i < 4; ++i)
        aw[i] = *(const f4*)&wqkv[(size_t)(o0 + ar + 32 * i) * DIM + k0 + k4];
      int sp = srm[bp];
#pragma unroll
      for (int i = 0; i < 16; ++i)
        bw[i] = xb[(size_t)(k0 + bc + i) * NPF + sp];
    }
    short8 af[4], bfr[4];
#pragma unroll
    for (int mi = 0; mi < 4; ++mi)
      af[mi] = *(const short8*)&sA[cur][(wm * 64 + mi * 16 + l15) * 40 + l4 * 8];
#pragma unroll
    for (int ni = 0; ni < 4; ++ni)
      bfr[ni] = *(const short8*)&sB[cur][(wn * 64 + ni * 16 + l15) * 40 + l4 * 8];
#pragma unroll
    for (int mi = 0; mi < 4; ++mi)
#pragma unroll
      for (int ni = 0; ni < 4; ++ni)
        acc[mi][ni] = MFMA(af[mi], bfr[ni], acc[mi][ni], 0, 0, 0);
    if (ks < 11) {
      int nxt = cur ^ 1;
#pragma unroll
      for (int i = 0; i < 4; ++i) {
        us4 u; u[0] = tob(aw[i][0]); u[1] = tob(aw[i][1]); u[2] = tob(aw[i][2]); u[3] = tob(aw[i][3]);
        *(us4*)&sA[nxt][(ar + 32 * i) * 40 + k4] = u;
      }
      us8 u0, u1;
#pragma unroll
      for (int i = 0; i < 8; ++i) u0[i] = tob(bw[i]);
#pragma unroll
      for (int i = 0; i < 8; ++i) u1[i] = tob(bw[8 + i]);
      *(us8*)&sB[nxt][bp * 40 + bc] = u0;
      *(us8*)&sB[nxt][bp * 40 + bc + 8] = u1;
    }
  }
  for (int mi = 0; mi < 4; ++mi)
    for (int ni = 0; ni < 4; ++ni)
      for (int r = 0; r < 4; ++r) {
        int o = o0 + wm * 64 + mi * 16 + (l4 << 2) + r;
        int p = p0 + wn * 64 + ni * 16 + l15;
        if (p < NPF)
          qkv[((size_t)b * 1152 + o) * NPF + p] = tob(acc[mi][ni][r]);
      }
}

__global__ __launch_bounds__(64) void k_attn_cm(ushort* __restrict__ qkv,
                                                const float* __restrict__ bias) {
  __shared__ __align__(16) ushort smem[8992];
  ushort* sq  = smem;
  ushort* skt = smem + 2560;
  ushort* svt = smem + 5120;
  ushort* stg = smem + 7424;
  ushort* pa  = smem;
  int t = threadIdx.x;
  int bid = blockIdx.x;
  int h = bid % HEADS, wb = bid / HEADS;
  int b = wb >> 6;
  int w49 = (wb & 63) * NPIX;
  size_t qb = ((size_t)b * 1152 + h * HD) * NPF;
  size_t kb = qb + (size_t)DIM * NPF;
  size_t vb = qb + (size_t)(2 * DIM) * NPF;
  for (int idx = t; idx < 32 * 23; idx += 64) {
    int d = idx / 23, mm = 49 + (idx - d * 23);
    svt[d * 72 + mm] = 0;
  }
  for (int idx = t; idx < HD * NPIX; idx += 64) stg[idx] = qkv[qb + (size_t)(idx / NPIX) * NPF + w49 + (idx % NPIX)];
  __syncthreads();
  for (int idx = t; idx < HD * NPIX; idx += 64) {
    int d = idx / NPIX, n = idx - d * NPIX;
    sq[n * 40 + d] = stg[idx];
  }
  for (int idx = t; idx < HD * NPIX; idx += 64) {
    int d = idx / NPIX, m = idx - d * NPIX;
    svt[d * 72 + m] = qkv[vb + (size_t)d * NPF + w49 + m];
  }
  __syncthreads();
  for (int idx = t; idx < HD * NPIX; idx += 64) stg[idx] = qkv[kb + (size_t)(idx / NPIX) * NPF + w49 + (idx % NPIX)];
  __syncthreads();
  for (int idx = t; idx < HD * NPIX; idx += 64) {
    int d = idx / NPIX, m = idx - d * NPIX;
    skt[m * 40 + d] = stg[idx];
  }
  __syncthreads();
  int l15 = t & 15, l4 = t >> 4;
  f32x4 acc[4][4] = {};
  {
    short8 af[4], bfr[4];
#pragma unroll
    for (int mi = 0; mi < 4; ++mi) af[mi]  = *(const short8*)&sq [(mi * 16 + l15) * 40 + l4 * 8];
#pragma unroll
    for (int ni = 0; ni < 4; ++ni) bfr[ni] = *(const short8*)&skt[(ni * 16 + l15) * 40 + l4 * 8];
#pragma unroll
    for (int mi = 0; mi < 4; ++mi)
#pragma unroll
      for (int ni = 0; ni < 4; ++ni)
        acc[mi][ni] = MFMA(af[mi], bfr[ni], acc[mi][ni], 0, 0, 0);
  }
  const float scale = 0.17677669529663687f;
  const float* bh = bias + h * NPIX * NPIX;
  float mx[16], sm[16];
#pragma unroll
  for (int mi = 0; mi < 4; ++mi)
#pragma unroll
    for (int r = 0; r < 4; ++r) {
      int n = mi * 16 + (l4 << 2) + r;
      float vmax = -3e38f;
#pragma unroll
      for (int ni = 0; ni < 4; ++ni) {
        int m = ni * 16 + l15;
        float s = (m < NPIX)
                    ? acc[mi][ni][r] * scale + ((n < NPIX) ? bh[n * NPIX + m] : 0.f)
                    : -3e38f;
        acc[mi][ni][r] = s;
        vmax = fmaxf(vmax, s);
      }
      mx[mi * 4 + r] = vmax;
    }
#pragma unroll
  for (int i = 1; i < 16; i <<= 1)
#pragma unroll
    for (int j = 0; j < 16; ++j) mx[j] = fmaxf(mx[j], __shfl_xor(mx[j], i));
#pragma unroll
  for (int mi = 0; mi < 4; ++mi)
#pragma unroll
    for (int r = 0; r < 4; ++r) {
      float s = 0.f;
#pragma unroll
      for (int ni = 0; ni < 4; ++ni) {
        float e = expf(acc[mi][ni][r] - mx[mi * 4 + r]);
        acc[mi][ni][r] = e;
        s += e;
      }
      sm[mi * 4 + r] = s;
    }
#pragma unroll
  for (int i = 1; i < 16; i <<= 1)
#pragma unroll
    for (int j = 0; j < 16; ++j) sm[j] += __shfl_xor(sm[j], i);
  __syncthreads();
#pragma unroll
  for (int mi = 0; mi < 4; ++mi)
#pragma unroll
    for (int r = 0; r < 4; ++r) {
      float ri = 1.f / sm[mi * 4 + r];
      int n = mi * 16 + (l4 << 2) + r;
#pragma unroll
      for (int ni = 0; ni < 4; ++ni)
        pa[n * 72 + ni * 16 + l15] = tob(acc[mi][ni][r] * ri);
    }
  __syncthreads();
  f32x4 yac[4][2] = {};
#pragma unroll
  for (int ks = 0; ks < 2; ++ks) {
    short8 pf[4], vf[2];
#pragma unroll
    for (int mi = 0; mi < 4; ++mi) pf[mi] = *(const short8*)&pa [(mi * 16 + l15) * 72 + ks * 32 + l4 * 8];
#pragma unroll
    for (int nd = 0; nd < 2; ++nd) vf[nd] = *(const short8*)&svt[(nd * 16 + l15) * 72 + ks * 32 + l4 * 8];
#pragma unroll
    for (int mi = 0; mi < 4; ++mi)
#pragma unroll
      for (int nd = 0; nd < 2; ++nd)
        yac[mi][nd] = MFMA(pf[mi], vf[nd], yac[mi][nd], 0, 0, 0);
  }
#pragma unroll
  for (int mi = 0; mi < 4; ++mi)
#pragma unroll
    for (int nd = 0; nd < 2; ++nd) {
      int nb = mi * 16 + (l4 << 2);
      int d = nd * 16 + l15;
      size_t ga = qb + (size_t)d * NPF + w49 + nb;
#pragma unroll
      for (int r = 0; r < 4; ++r)
        if (nb + r < NPIX) qkv[ga + r] = tob(yac[mi][nd][r]);
    }
}

__global__ __launch_bounds__(256) void k_proj_cm(const ushort* __restrict__ yq,
                                                 const float* __restrict__ wproj,
                                                 float* __restrict__ out) {
  __shared__ __align__(16) ushort sA[2][128 * 40];
  __shared__ __align__(16) ushort sB[2][128 * 40];
  __shared__ int srm[128];
  int t   = threadIdx.x;
  int bid = blockIdx.x;
  int swz = (bid & 7) * 150 + (bid >> 3);
  int o0  = (swz % 3) * 128;
  int pb  = swz / 3;
  int p0  = (pb % 25) * 128;
  int b   = pb / 25;
  if (t < 128) {
    int pg = p0 + t;
    if (pg >= NPF) pg = 0;
    int si = (pg / IMG + 53) % IMG, sj = (pg % IMG + 53) % IMG;
    srm[t] = ((si / WIN) * 8 + sj / WIN) * NPIX + (si % WIN) * WIN + (sj % WIN);
  }
  __syncthreads();
  int lane = t & 63, w = t >> 6;
  int wm = w >> 1, wn = w & 1;
  int l15 = lane & 15, l4 = lane >> 4;
  int k4 = (t & 7) * 4, ar = t >> 3;
  int bp = t & 127, bc = (t >> 7) << 4;
  const ushort* yb = yq + (size_t)b * 1152 * NPF;
  f32x4 acc[4][4] = {};
  {
#pragma unroll
    for (int i = 0; i < 4; ++i) {
      int row = ar + 32 * i;
      f4 v = *(const f4*)&wproj[(size_t)(o0 + row) * DIM + k4];
      us4 u; u[0] = tob(v[0]); u[1] = tob(v[1]); u[2] = tob(v[2]); u[3] = tob(v[3]);
      *(us4*)&sA[0][row * 40 + k4] = u;
    }
    int sp = srm[bp];
    us8 u0, u1;
#pragma unroll
    for (int i = 0; i < 8; ++i) u0[i] = yb[(size_t)(bc + i) * NPF + sp];
#pragma unroll
    for (int i = 0; i < 8; ++i) u1[i] = yb[(size_t)(bc + 8 + i) * NPF + sp];
    *(us8*)&sB[0][bp * 40 + bc] = u0;
    *(us8*)&sB[0][bp * 40 + bc + 8] = u1;
  }
  for (int ks = 0; ks < 12; ++ks) {
    __syncthreads();
    int cur = ks & 1;
    f4 aw[4]; ushort bw[16];
    if (ks < 11) {
      int k0 = (ks + 1) * 32;
#pragma unroll
      for (int i = 0; i < 4; ++i)
        aw[i] = *(const f4*)&wproj[(size_t)(o0 + ar + 32 * i) * DIM + k0 + k4];
      int sp = srm[bp];
#pragma unroll
      for (int i = 0; i < 16; ++i)
        bw[i] = yb[(size_t)(k0 + bc + i) * NPF + sp];
    }
    short8 af[4], bfr[4];
#pragma unroll
    for (int mi = 0; mi < 4; ++mi)
      af[mi] = *(const short8*)&sA[cur][(wm * 64 + mi * 16 + l15) * 40 + l4 * 8];
#pragma unroll
    for (int ni = 0; ni < 4; ++ni)
      bfr[ni] = *(const short8*)&sB[cur][(wn * 64 + ni * 16 + l15) * 40 + l4 * 8];
#pragma unroll
    for (int mi = 0; mi < 4; ++mi)
#pragma unroll
      for (int ni = 0; ni < 4; ++ni)
        acc[mi][ni] = MFMA(af[mi], bfr[ni], acc[mi][ni], 0, 0, 0);
    if (ks < 11) {
      int nxt = cur ^ 1;
#pragma unroll
      for (int i = 0; i < 4; ++i) {
        us4 u; u[0] = tob(aw[i][0]); u[1] = tob(aw[i][1]); u[2] = tob(aw[i][2]); u[3] = tob(aw[i][3]);
        *(us4*)&sA[nxt][(ar + 32 * i) * 40 + k4] = u;
      }
      us8 u0, u1;
#pragma unroll
      for (int i = 0; i < 8; ++i) u0[i] = bw[i];
#pragma unroll
      for (int i = 0; i < 8; ++i) u1[i] = bw[8 + i];
      *(us8*)&sB[nxt][bp * 40 + bc] = u0;
      *(us8*)&sB[nxt][bp * 40 + bc + 8] = u1;
    }
  }
  for (int mi = 0; mi < 4; ++mi)
    for (int ni = 0; ni < 4; ++ni)
      for (int r = 0; r < 4; ++r) {
        int o = o0 + wm * 64 + mi * 16 + (l4 << 2) + r;
        int p = p0 + wn * 64 + ni * 16 + l15;
        if (p < NPF)
          out[((size_t)b * DIM + o) * NPF + p] = acc[mi][ni][r];
      }
}

extern "C" void kernel_launch(void* const* d_in, const int* in_sizes, int n_in,
                              void* d_out, int out_size, void* d_ws, size_t ws_size,
                              hipStream_t stream) {
  const float* x     = (const float*)d_in[0];
  const float* wqkv  = (const float*)d_in[1];
  const float* wproj = (const float*)d_in[2];
  const float* cpb   = (const float*)d_in[3];
  float* out = (float*)d_out;

  char* ws = (char*)d_ws;
  float* bias = (float*)ws;                    // 115248 B
  int*   rmap = (int*)(ws + 115712);           // 12544 B -> 131072

  hipLaunchKernelGGL(k_bias, dim3(113), dim3(256), 0, stream, cpb, bias);
  hipLaunchKernelGGL(k_rmap, dim3(13), dim3(256), 0, stream, rmap);

  const size_t QKV_B = (size_t)16 * 1152 * NPF * 2;       // 115,605,504
  const size_t XW_B  = (size_t)16 * NPF * DIM * 2;        // 38,535,168
  const size_t need  = 1310720 + QKV_B + XW_B;            // 155,451,392

  if (ws_size >= need) {
    ushort* wqb = (ushort*)(ws + 131072);                 // 884736 B
    ushort* wpb = (ushort*)(ws + 1015808);                // 294912 B -> 1310720
    ushort* qkv = (ushort*)(ws + 1310720);
    ushort* xw  = (ushort*)(ws + 1310720 + QKV_B);
    hipLaunchKernelGGL(k_wcvt, dim3(288), dim3(256), 0, stream, wqkv, wproj, wqb, wpb);
    hipLaunchKernelGGL(k_xw, dim3(196), dim3(256), 0, stream, x, rmap, xw);
    hipLaunchKernelGGL(k_qkv_pm, dim3(1872), dim3(256), 0, stream, xw, wqb, qkv);
    hipLaunchKernelGGL(k_attn_pm, dim3(NWIN * HEADS), dim3(64), 0, stream, qkv, bias);
    hipLaunchKernelGGL(k_proj_pm, dim3(1200), dim3(256), 0, stream, qkv, wpb, out);
  } else {
    ushort* qkv = (ushort*)(ws + 131072);
    hipLaunchKernelGGL(k_qkv_cm, dim3(3600), dim3(256), 0, stream, x, wqkv, rmap, qkv);
    hipLaunchKernelGGL(k_attn_cm, dim3(NWIN * HEADS), dim3(64), 0, stream, qkv, bias);
    hipLaunchKernelGGL(k_proj_cm, dim3(1200), dim3(256), 0, stream, qkv, wproj, out);
  }
}